// Round 14
// baseline (8534.106 us; speedup 1.0000x reference)
//
#include <hip/hip_runtime.h>
#include <math.h>

#define B_TOT 2048
#define T_LEN 512
#define HDIM 64
#define FC1 50
#define NSUP 514   // skew-2 pair: 512 + 2

typedef __bf16 bf16x8 __attribute__((ext_vector_type(8)));
typedef float f32x4 __attribute__((ext_vector_type(4)));
typedef unsigned int u32x4 __attribute__((ext_vector_type(4)));

// Fast transcendentals (no -ffast-math in harness; "/" would emit 12-inst IEEE div)
__device__ __forceinline__ float vrcp(float x) {
  float r; asm("v_rcp_f32 %0, %1" : "=v"(r) : "v"(x)); return r;
}
__device__ __forceinline__ float vexp2(float x) {
  float r; asm("v_exp_f32 %0, %1" : "=v"(r) : "v"(x)); return r;
}
__device__ __forceinline__ float sigm(float x) {
  return vrcp(1.0f + vexp2(x * -1.44269504088896340736f));
}
__device__ __forceinline__ float tanh_(float x) {
  return fmaf(2.0f, vrcp(1.0f + vexp2(x * -2.8853900817779268f)), -1.0f);
}

// lgkm-only barrier: LDS visibility without draining global queues.
#define BARRIER() asm volatile("s_waitcnt lgkmcnt(0)\n\ts_barrier" ::: "memory")
#define MFMA __builtin_amdgcn_mfma_f32_16x16x32_bf16

// Planar [16][64] bf16, 16B-chunk XOR swizzle: full-wave b128 = uniform 8 lanes/bank-group.
#define HADDR(row, chunk) (((row) << 6) + ((((chunk) ^ ((row) & 7))) << 3))

__device__ __forceinline__ void unpk(u32x4 p0, u32x4 p1, bf16x8* hi, bf16x8* lo) {
  u32x4 h, l;
  h[0] = __builtin_amdgcn_perm(p0[1], p0[0], 0x05040100u);
  h[1] = __builtin_amdgcn_perm(p0[3], p0[2], 0x05040100u);
  h[2] = __builtin_amdgcn_perm(p1[1], p1[0], 0x05040100u);
  h[3] = __builtin_amdgcn_perm(p1[3], p1[2], 0x05040100u);
  l[0] = __builtin_amdgcn_perm(p0[1], p0[0], 0x07060302u);
  l[1] = __builtin_amdgcn_perm(p0[3], p0[2], 0x07060302u);
  l[2] = __builtin_amdgcn_perm(p1[1], p1[0], 0x07060302u);
  l[3] = __builtin_amdgcn_perm(p1[3], p1[2], 0x07060302u);
  *hi = __builtin_bit_cast(bf16x8, h);
  *lo = __builtin_bit_cast(bf16x8, l);
}

// ---------- Skew-2 pair kernel: 8-ROW tiles, 2 blocks/CU oversubscription ----
// R14: grid 256 (8 batch rows/block). MFMA rows 8-15 compute clamped-duplicate
// garbage (confined to D rows 8-15, which are store-masked); valid rows 0-7
// are bit-identical to R13. Two independent blocks per CU fill each other's
// dependency stalls (chain is latency-bound, 2970cy wall vs 850cy issue).
#define SUPERQ(N_, P_)                                                         \
  {                                                                            \
    if (set == 0) {                                                            \
      if ((N_) < T_LEN) {                                                      \
        bf16x8 ahh0 = *(const bf16x8*)&Hhi[0][1 - (P_)][HADDR(nn, cg)];        \
        bf16x8 ahh1 = *(const bf16x8*)&Hhi[0][1 - (P_)][HADDR(nn, 4 + cg)];    \
        bf16x8 ahl0 = *(const bf16x8*)&Hlo[0][1 - (P_)][HADDR(nn, cg)];        \
        bf16x8 ahl1 = *(const bf16x8*)&Hlo[0][1 - (P_)][HADDR(nn, 4 + cg)];    \
        f32x4 accs[4];                                                         \
        _Pragma("unroll") for (int g = 0; g < 4; ++g) {                        \
          f32x4 a = xacc[P_][g];                                               \
          a = MFMA(ahh0, bhh[g][0], a, 0, 0, 0);                               \
          a = MFMA(ahh1, bhh[g][1], a, 0, 0, 0);                               \
          a = MFMA(ahl0, bhh[g][0], a, 0, 0, 0);                               \
          a = MFMA(ahl1, bhh[g][1], a, 0, 0, 0);                               \
          accs[g] = a;                                                         \
        }                                                                      \
        _Pragma("unroll") for (int r = 0; r < 4; ++r) {                        \
          float iv = sigm(accs[0][r]);                                         \
          float fv = sigm(accs[1][r]);                                         \
          float gv = tanh_(accs[2][r]);                                        \
          float ov = sigm(accs[3][r]);                                         \
          cell[r] = fv * cell[r] + iv * gv;                                    \
          float hv = ov * tanh_(cell[r]);                                      \
          __bf16 h1 = (__bf16)hv;                                              \
          __bf16 h2 = (__bf16)(hv - (float)h1);                                \
          int mrow = 4 * cg + r;                                               \
          int ha = HADDR(mrow, uu >> 3) + (uu & 7);                            \
          Hhi[0][P_][ha] = h1;                                                 \
          Hlo[0][P_][ha] = h2;                                                 \
        }                                                                      \
      }                                                                        \
      /* tail: x-seed for t = N_+1 */                                         \
      if ((N_) + 1 < T_LEN) {                                                  \
        if (XIN) {                                                             \
          _Pragma("unroll") for (int g = 0; g < 4; ++g) {                      \
            f32x4 a;                                                           \
            _Pragma("unroll") for (int r = 0; r < 4; ++r)                      \
              a[r] = bias[g] + xw[g*3+0] * xr[P_][r*3+0]                       \
                             + xw[g*3+1] * xr[P_][r*3+1]                       \
                             + xw[g*3+2] * xr[P_][r*3+2];                      \
            xacc[1 - (P_)][g] = a;                                             \
          }                                                                    \
        } else {                                                               \
          bf16x8 xh0, xl0, xh1, xl1;                                           \
          unpk(xpk[P_][0], xpk[P_][1], &xh0, &xl0);                            \
          unpk(xpk[P_][2], xpk[P_][3], &xh1, &xl1);                            \
          _Pragma("unroll") for (int g = 0; g < 4; ++g) {                      \
            f32x4 a = {bias[g], bias[g], bias[g], bias[g]};                    \
            a = MFMA(xh0, bih[g][0], a, 0, 0, 0);                              \
            a = MFMA(xh1, bih[g][1], a, 0, 0, 0);                              \
            a = MFMA(xl0, bih[g][0], a, 0, 0, 0);                              \
            a = MFMA(xl1, bih[g][1], a, 0, 0, 0);                              \
            xacc[1 - (P_)][g] = a;                                             \
          }                                                                    \
        }                                                                      \
      }                                                                        \
      {                                                                        \
        int tp = (N_) + 3; if (tp > T_LEN - 1) tp = T_LEN - 1;                 \
        if (XIN) {                                                             \
          _Pragma("unroll") for (int r = 0; r < 4; ++r)                        \
            _Pragma("unroll") for (int i = 0; i < 3; ++i)                      \
              xr[P_][r*3+i] =                                                  \
                  x_f32[((size_t)(bbase + ((4*cg + r) & 7)) * T_LEN + tp) * 3 + i]; \
        } else {                                                               \
          const unsigned int* px = seqp + xrow + (size_t)tp * HDIM;            \
          xpk[P_][0] = *(const u32x4*)(px + 8 * cg);                           \
          xpk[P_][1] = *(const u32x4*)(px + 8 * cg + 4);                       \
          xpk[P_][2] = *(const u32x4*)(px + 32 + 8 * cg);                      \
          xpk[P_][3] = *(const u32x4*)(px + 32 + 8 * cg + 4);                  \
        }                                                                      \
      }                                                                        \
    } else {                                                                   \
      if ((N_) >= 2) {                                                         \
        const int tl = (N_) - 2;                                               \
        bf16x8 ahh0 = *(const bf16x8*)&Hhi[1][1 - (P_)][HADDR(nn, cg)];        \
        bf16x8 ahh1 = *(const bf16x8*)&Hhi[1][1 - (P_)][HADDR(nn, 4 + cg)];    \
        bf16x8 ahl0 = *(const bf16x8*)&Hlo[1][1 - (P_)][HADDR(nn, cg)];        \
        bf16x8 ahl1 = *(const bf16x8*)&Hlo[1][1 - (P_)][HADDR(nn, 4 + cg)];    \
        f32x4 accs[4];                                                         \
        _Pragma("unroll") for (int g = 0; g < 4; ++g) {                        \
          f32x4 a = xacc[P_][g];                                               \
          a = MFMA(ahh0, bhh[g][0], a, 0, 0, 0);                               \
          a = MFMA(ahh1, bhh[g][1], a, 0, 0, 0);                               \
          a = MFMA(ahl0, bhh[g][0], a, 0, 0, 0);                               \
          a = MFMA(ahl1, bhh[g][1], a, 0, 0, 0);                               \
          accs[g] = a;                                                         \
        }                                                                      \
        _Pragma("unroll") for (int r = 0; r < 4; ++r) {                        \
          float iv = sigm(accs[0][r]);                                         \
          float fv = sigm(accs[1][r]);                                         \
          float gv = tanh_(accs[2][r]);                                        \
          float ov = sigm(accs[3][r]);                                         \
          cell[r] = fv * cell[r] + iv * gv;                                    \
          float hv = ov * tanh_(cell[r]);                                      \
          __bf16 h1 = (__bf16)hv;                                              \
          __bf16 h2 = (__bf16)(hv - (float)h1);                                \
          int mrow = 4 * cg + r;                                               \
          int ha = HADDR(mrow, uu >> 3) + (uu & 7);                            \
          Hhi[1][P_][ha] = h1;                                                 \
          Hlo[1][P_][ha] = h2;                                                 \
          if (mrow < 8) {                                                      \
            unsigned int hb = (unsigned int)__builtin_bit_cast(unsigned short, h1) \
                            | ((unsigned int)__builtin_bit_cast(unsigned short, h2) << 16); \
            seqp[((size_t)(bbase + mrow) * T_LEN + tl) * HDIM + uu] = hb;      \
          }                                                                    \
        }                                                                      \
      }                                                                        \
      /* tail: x-seed for t = N_-1 from upstream h0(N_-1), written pre-barrier */ \
      if ((N_) >= 1 && (N_) - 1 < T_LEN) {                                     \
        bf16x8 xh0 = *(const bf16x8*)&Hhi[0][1 - (P_)][HADDR(nn, cg)];         \
        bf16x8 xh1 = *(const bf16x8*)&Hhi[0][1 - (P_)][HADDR(nn, 4 + cg)];     \
        bf16x8 xl0 = *(const bf16x8*)&Hlo[0][1 - (P_)][HADDR(nn, cg)];         \
        bf16x8 xl1 = *(const bf16x8*)&Hlo[0][1 - (P_)][HADDR(nn, 4 + cg)];     \
        _Pragma("unroll") for (int g = 0; g < 4; ++g) {                        \
          f32x4 a = {bias[g], bias[g], bias[g], bias[g]};                      \
          a = MFMA(xh0, bih[g][0], a, 0, 0, 0);                                \
          a = MFMA(xh1, bih[g][1], a, 0, 0, 0);                                \
          a = MFMA(xl0, bih[g][0], a, 0, 0, 0);                                \
          a = MFMA(xl1, bih[g][1], a, 0, 0, 0);                                \
          xacc[1 - (P_)][g] = a;                                               \
        }                                                                      \
      }                                                                        \
    }                                                                          \
    BARRIER();                                                                 \
  }

template<int L0, bool XIN>
__global__ __launch_bounds__(512, 4)   // 4 waves/EU -> 2 blocks/CU
void lstm_pairq(const float* __restrict__ x_f32,
                const float* __restrict__ w_ih0,
                const float* __restrict__ w_ih_rest,
                const float* __restrict__ w_hh,
                const float* __restrict__ b_ih,
                const float* __restrict__ b_hh,
                unsigned int* __restrict__ seqp)
{
  const int tid  = threadIdx.x;
  const int lane = tid & 63;
  const int wv   = tid >> 6;
  const int set  = wv >> 2;       // 0,1 (wave-uniform)
  const int wq   = wv & 3;
  const int nn   = lane & 15;
  const int cg   = lane >> 4;
  const int bbase = blockIdx.x * 8;
  const int grow = 16 * wq + nn;
  const int uu   = grow;
  const int layer = L0 + set;

  __shared__ __align__(16) __bf16 Hhi[2][2][1024];  // 8 KB
  __shared__ __align__(16) __bf16 Hlo[2][2][1024];  // 8 KB

  bf16x8 bhh[4][2];
#pragma unroll
  for (int g = 0; g < 4; ++g)
#pragma unroll
    for (int kk = 0; kk < 2; ++kk) {
      const float* wp = w_hh + (size_t)layer * 256 * 64
                      + (size_t)(64 * g + grow) * 64 + kk * 32 + 8 * cg;
      bf16x8 t;
#pragma unroll
      for (int e = 0; e < 8; ++e) t[e] = (__bf16)wp[e];
      bhh[g][kk] = t;
    }
  bf16x8 bih[4][2];
  float xw[12];
  if (XIN && set == 0) {
#pragma unroll
    for (int g = 0; g < 4; ++g)
#pragma unroll
      for (int i = 0; i < 3; ++i) xw[g * 3 + i] = w_ih0[(64 * g + grow) * 3 + i];
  } else {
    const float* wih_l = w_ih_rest + (size_t)(layer - 1) * 256 * 64;
#pragma unroll
    for (int g = 0; g < 4; ++g)
#pragma unroll
      for (int kk = 0; kk < 2; ++kk) {
        const float* wp = wih_l + (size_t)(64 * g + grow) * 64 + kk * 32 + 8 * cg;
        bf16x8 t;
#pragma unroll
        for (int e = 0; e < 8; ++e) t[e] = (__bf16)wp[e];
        bih[g][kk] = t;
      }
  }
  float bias[4];
#pragma unroll
  for (int g = 0; g < 4; ++g) {
    int row = layer * 256 + 64 * g + grow;
    bias[g] = b_ih[row] + b_hh[row];
  }

  for (int q = tid; q < 4 * 1024; q += 512) {
    ((__bf16*)Hhi)[q] = (__bf16)0.f;
    ((__bf16*)Hlo)[q] = (__bf16)0.f;
  }

  float cell[4] = {0.f, 0.f, 0.f, 0.f};
  // rows 8-15 mirror rows 0-7 (clamped) -> in-bounds, garbage confined
  const size_t xrow = (size_t)(bbase + (nn & 7)) * T_LEN * HDIM;

  f32x4 xacc[2][4];
  float xr[2][12];
  u32x4 xpk[2][4];

  if (set == 0) {
    if (XIN) {
      float x0[12];
#pragma unroll
      for (int r = 0; r < 4; ++r)
#pragma unroll
        for (int i = 0; i < 3; ++i)
          x0[r*3+i] = x_f32[((size_t)(bbase + ((4*cg + r) & 7)) * T_LEN + 0) * 3 + i];
#pragma unroll
      for (int g = 0; g < 4; ++g) {
        f32x4 a;
#pragma unroll
        for (int r = 0; r < 4; ++r)
          a[r] = bias[g] + xw[g*3+0]*x0[r*3+0] + xw[g*3+1]*x0[r*3+1] + xw[g*3+2]*x0[r*3+2];
        xacc[0][g] = a;
      }
#pragma unroll
      for (int p = 0; p < 2; ++p)
#pragma unroll
        for (int r = 0; r < 4; ++r)
#pragma unroll
          for (int i = 0; i < 3; ++i)
            xr[p][r*3+i] = x_f32[((size_t)(bbase + ((4*cg + r) & 7)) * T_LEN + (p + 1)) * 3 + i];
    } else {
      const unsigned int* px = seqp + xrow;
      u32x4 q0 = *(const u32x4*)(px + 8 * cg);
      u32x4 q1 = *(const u32x4*)(px + 8 * cg + 4);
      u32x4 q2 = *(const u32x4*)(px + 32 + 8 * cg);
      u32x4 q3 = *(const u32x4*)(px + 32 + 8 * cg + 4);
      bf16x8 xh0, xl0, xh1, xl1;
      unpk(q0, q1, &xh0, &xl0);
      unpk(q2, q3, &xh1, &xl1);
#pragma unroll
      for (int g = 0; g < 4; ++g) {
        f32x4 a = {bias[g], bias[g], bias[g], bias[g]};
        a = MFMA(xh0, bih[g][0], a, 0, 0, 0);
        a = MFMA(xh1, bih[g][1], a, 0, 0, 0);
        a = MFMA(xl0, bih[g][0], a, 0, 0, 0);
        a = MFMA(xl1, bih[g][1], a, 0, 0, 0);
        xacc[0][g] = a;
      }
#pragma unroll
      for (int p = 0; p < 2; ++p) {
        const unsigned int* pq = seqp + xrow + (size_t)(p + 1) * HDIM;
        xpk[p][0] = *(const u32x4*)(pq + 8 * cg);
        xpk[p][1] = *(const u32x4*)(pq + 8 * cg + 4);
        xpk[p][2] = *(const u32x4*)(pq + 32 + 8 * cg);
        xpk[p][3] = *(const u32x4*)(pq + 32 + 8 * cg + 4);
      }
    }
  }
  __syncthreads();

  for (int n = 0; n < NSUP; n += 2) {
    SUPERQ(n,     0);
    SUPERQ(n + 1, 1);
  }
}

// -------------- Single-layer kernel (8-row tiles, layer 4) ---------------
#define STEP(T0, P)                                                            \
  {                                                                            \
    if (isA) {                                                                 \
      bf16x8 ahh0 = *(const bf16x8*)&h_hi[P][HADDR(nn, cg)];                   \
      bf16x8 ahh1 = *(const bf16x8*)&h_hi[P][HADDR(nn, 4 + cg)];               \
      bf16x8 ahl0 = *(const bf16x8*)&h_lo[P][HADDR(nn, cg)];                   \
      bf16x8 ahl1 = *(const bf16x8*)&h_lo[P][HADDR(nn, 4 + cg)];               \
      f32x4 accs[4];                                                           \
      _Pragma("unroll")                                                        \
      for (int g = 0; g < 4; ++g) {                                            \
        f32x4 a = accx[P][g][wq * 64 + lane];                                  \
        a = MFMA(ahh0, bhh[g][0], a, 0, 0, 0);                                 \
        a = MFMA(ahh1, bhh[g][1], a, 0, 0, 0);                                 \
        a = MFMA(ahl0, bhh[g][0], a, 0, 0, 0);                                 \
        a = MFMA(ahl1, bhh[g][1], a, 0, 0, 0);                                 \
        accs[g] = a;                                                           \
      }                                                                        \
      _Pragma("unroll")                                                        \
      for (int r = 0; r < 4; ++r) {                                            \
        float iv = sigm(accs[0][r]);                                           \
        float fv = sigm(accs[1][r]);                                           \
        float gv = tanh_(accs[2][r]);                                          \
        float ov = sigm(accs[3][r]);                                           \
        cell[r] = fv * cell[r] + iv * gv;                                      \
        float hv = ov * tanh_(cell[r]);                                        \
        __bf16 h1 = (__bf16)hv;                                                \
        __bf16 h2 = (__bf16)(hv - (float)h1);                                  \
        int mrow = 4 * cg + r;                                                 \
        int ha = HADDR(mrow, uu >> 3) + (uu & 7);                              \
        h_hi[1 - (P)][ha] = h1;                                                \
        h_lo[1 - (P)][ha] = h2;                                                \
      }                                                                        \
    } else {                                                                   \
      if ((T0) > 0) {                                                          \
        _Pragma("unroll")                                                      \
        for (int r = 0; r < 4; ++r) {                                          \
          int mrow = 4 * cg + r;                                               \
          int ha = HADDR(mrow, uu >> 3) + (uu & 7);                            \
          if (mrow < 8) {                                                      \
            unsigned int hb =                                                  \
                (unsigned int)__builtin_bit_cast(unsigned short, h_hi[P][ha])  \
              | ((unsigned int)__builtin_bit_cast(unsigned short, h_lo[P][ha]) << 16); \
            seqp[((size_t)(bbase + mrow) * T_LEN + (T0) - 1) * HDIM + uu] = hb;\
          }                                                                    \
        }                                                                      \
      }                                                                        \
      if ((T0) + 1 < T_LEN) {                                                  \
        bf16x8 xh0, xl0, xh1, xl1;                                             \
        unpk(xpk[P][0], xpk[P][1], &xh0, &xl0);                                \
        unpk(xpk[P][2], xpk[P][3], &xh1, &xl1);                                \
        _Pragma("unroll")                                                      \
        for (int g = 0; g < 4; ++g) {                                          \
          f32x4 a = {bias[g], bias[g], bias[g], bias[g]};                      \
          a = MFMA(xh0, bih[g][0], a, 0, 0, 0);                                \
          a = MFMA(xh1, bih[g][1], a, 0, 0, 0);                                \
          a = MFMA(xl0, bih[g][0], a, 0, 0, 0);                                \
          a = MFMA(xl1, bih[g][1], a, 0, 0, 0);                                \
          accx[1 - (P)][g][wq * 64 + lane] = a;                                \
        }                                                                      \
      }                                                                        \
      {                                                                        \
        int tp = (T0) + 3; if (tp >= T_LEN) tp = T_LEN - 1;                    \
        const unsigned int* px = seqp + xrow + (size_t)tp * HDIM;              \
        xpk[P][0] = *(const u32x4*)(px + 8 * cg);                              \
        xpk[P][1] = *(const u32x4*)(px + 8 * cg + 4);                          \
        xpk[P][2] = *(const u32x4*)(px + 32 + 8 * cg);                         \
        xpk[P][3] = *(const u32x4*)(px + 32 + 8 * cg + 4);                     \
      }                                                                        \
    }                                                                          \
    BARRIER();                                                                 \
  }

__global__ __launch_bounds__(512, 4)   // 2 blocks/CU
void lstm_single(const float* __restrict__ w_ih,
                 const float* __restrict__ w_hh,
                 const float* __restrict__ b_ih,
                 const float* __restrict__ b_hh,
                 unsigned int* seqp)
{
    const int tid  = threadIdx.x;
    const int lane = tid & 63;
    const int wv   = tid >> 6;
    const bool isA = (wv < 4);
    const int wq   = wv & 3;
    const int nn   = lane & 15;
    const int cg   = lane >> 4;
    const int bbase = blockIdx.x * 8;
    const int grow = 16 * wq + nn;
    const int uu   = grow;

    __shared__ __align__(16) __bf16 h_hi[2][16 * 64];
    __shared__ __align__(16) __bf16 h_lo[2][16 * 64];
    __shared__ __align__(16) f32x4 accx[2][4][256];

    bf16x8 bhh[4][2];
    bf16x8 bih[4][2];
    float bias[4];
    if (isA) {
#pragma unroll
      for (int g = 0; g < 4; ++g)
#pragma unroll
        for (int kk = 0; kk < 2; ++kk) {
          const float* wp = w_hh + (size_t)(64 * g + grow) * 64 + kk * 32 + 8 * cg;
          bf16x8 t;
#pragma unroll
          for (int e = 0; e < 8; ++e) t[e] = (__bf16)wp[e];
          bhh[g][kk] = t;
        }
    } else {
#pragma unroll
      for (int g = 0; g < 4; ++g) {
        int row = 64 * g + grow;
        bias[g] = b_ih[row] + b_hh[row];
      }
#pragma unroll
      for (int g = 0; g < 4; ++g)
#pragma unroll
        for (int kk = 0; kk < 2; ++kk) {
          const float* wp = w_ih + (size_t)(64 * g + grow) * 64 + kk * 32 + 8 * cg;
          bf16x8 t;
#pragma unroll
          for (int e = 0; e < 8; ++e) t[e] = (__bf16)wp[e];
          bih[g][kk] = t;
        }
    }

    for (int q = tid; q < 1024; q += 512) {
      h_hi[0][q] = (__bf16)0.f; h_hi[1][q] = (__bf16)0.f;
      h_lo[0][q] = (__bf16)0.f; h_lo[1][q] = (__bf16)0.f;
    }

    float cell[4] = {0.f, 0.f, 0.f, 0.f};
    const size_t xrow = (size_t)(bbase + (nn & 7)) * T_LEN * HDIM;
    u32x4 xpk[2][4];

    if (!isA) {
      const unsigned int* px = seqp + xrow;
      u32x4 q0 = *(const u32x4*)(px + 8 * cg);
      u32x4 q1 = *(const u32x4*)(px + 8 * cg + 4);
      u32x4 q2 = *(const u32x4*)(px + 32 + 8 * cg);
      u32x4 q3 = *(const u32x4*)(px + 32 + 8 * cg + 4);
      bf16x8 xh0, xl0, xh1, xl1;
      unpk(q0, q1, &xh0, &xl0);
      unpk(q2, q3, &xh1, &xl1);
#pragma unroll
      for (int g = 0; g < 4; ++g) {
        f32x4 a = {bias[g], bias[g], bias[g], bias[g]};
        a = MFMA(xh0, bih[g][0], a, 0, 0, 0);
        a = MFMA(xh1, bih[g][1], a, 0, 0, 0);
        a = MFMA(xl0, bih[g][0], a, 0, 0, 0);
        a = MFMA(xl1, bih[g][1], a, 0, 0, 0);
        accx[0][g][wq * 64 + lane] = a;
      }
#pragma unroll
      for (int p = 0; p < 2; ++p) {
        const unsigned int* pq = seqp + xrow + (size_t)(p + 1) * HDIM;
        xpk[p][0] = *(const u32x4*)(pq + 8 * cg);
        xpk[p][1] = *(const u32x4*)(pq + 8 * cg + 4);
        xpk[p][2] = *(const u32x4*)(pq + 32 + 8 * cg);
        xpk[p][3] = *(const u32x4*)(pq + 32 + 8 * cg + 4);
      }
    }
    __syncthreads();

    if (isA) __builtin_amdgcn_s_setprio(1);
    for (int t = 0; t < T_LEN; t += 2) {
      STEP(t, 0);
      STEP(t + 1, 1);
    }
    if (isA) __builtin_amdgcn_s_setprio(0);

    if (!isA) {
#pragma unroll
      for (int r = 0; r < 4; ++r) {
        int mrow = 4 * cg + r;
        int ha = HADDR(mrow, uu >> 3) + (uu & 7);
        if (mrow < 8) {
          unsigned int hb =
              (unsigned int)__builtin_bit_cast(unsigned short, h_hi[0][ha])
            | ((unsigned int)__builtin_bit_cast(unsigned short, h_lo[0][ha]) << 16);
          seqp[((size_t)(bbase + mrow) * T_LEN + (T_LEN - 1)) * HDIM + uu] = hb;
        }
      }
    }
}

// FC head: out[b] = fc2_b + fc2_w . relu(fc1_b + fc1_w . h_T[b])
__global__ __launch_bounds__(256, 1)
void fc_head(const unsigned int* __restrict__ seqp,
             const float* __restrict__ fc1_w, const float* __restrict__ fc1_b,
             const float* __restrict__ fc2_w, const float* __restrict__ fc2_b,
             float* __restrict__ out)
{
    __shared__ float w1[FC1 * HDIM];
    __shared__ float b1[FC1];
    __shared__ float w2[FC1];
    const int tid = threadIdx.x;
    for (int i = tid; i < FC1 * HDIM; i += 256) w1[i] = fc1_w[i];
    if (tid < FC1) { b1[tid] = fc1_b[tid]; w2[tid] = fc2_w[tid]; }
    __syncthreads();

    const int b = blockIdx.x * 256 + tid;
    const size_t base = ((size_t)b * T_LEN + (T_LEN - 1)) * HDIM;
    float h[HDIM];
#pragma unroll
    for (int q = 0; q < HDIM; ++q) {
      unsigned int v = seqp[base + q];
      float hi = (float)__builtin_bit_cast(__bf16, (unsigned short)(v & 0xffffu));
      float lo = (float)__builtin_bit_cast(__bf16, (unsigned short)(v >> 16));
      h[q] = hi + lo;
    }
    float acc2 = fc2_b[0];
    for (int m = 0; m < FC1; ++m) {
      float a = b1[m];
#pragma unroll
      for (int q = 0; q < HDIM; ++q) a += w1[m * HDIM + q] * h[q];
      acc2 += w2[m] * fmaxf(a, 0.0f);
    }
    out[b] = acc2;
}

extern "C" void kernel_launch(void* const* d_in, const int* in_sizes, int n_in,
                              void* d_out, int out_size, void* d_ws, size_t ws_size,
                              hipStream_t stream) {
    const float* x         = (const float*)d_in[0];
    const float* w_ih0     = (const float*)d_in[1];
    const float* w_ih_rest = (const float*)d_in[2];
    const float* w_hh      = (const float*)d_in[3];
    const float* b_ih      = (const float*)d_in[4];
    const float* b_hh      = (const float*)d_in[5];
    const float* fc1_w     = (const float*)d_in[6];
    const float* fc1_b     = (const float*)d_in[7];
    const float* fc2_w     = (const float*)d_in[8];
    const float* fc2_b     = (const float*)d_in[9];
    float* out = (float*)d_out;

    unsigned int* seqp = (unsigned int*)d_ws;   // [B,T,64] packed = 256 MiB

    // layers 0+1, skew-2 pair, 8-row tiles (256 blocks, 2/CU); writes seq1
    lstm_pairq<0, true><<<dim3(B_TOT / 8), dim3(512), 0, stream>>>(
        x, w_ih0, w_ih_rest, w_hh, b_ih, b_hh, seqp);
    // layers 2+3; reads seq1 / writes seq3 in-place (gap >= 5)
    lstm_pairq<2, false><<<dim3(B_TOT / 8), dim3(512), 0, stream>>>(
        x, w_ih0, w_ih_rest, w_hh, b_ih, b_hh, seqp);
    // layer 4; reads seq3 / writes seq4 in-place (gap 4)
    lstm_single<<<dim3(B_TOT / 8), dim3(512), 0, stream>>>(
        w_ih_rest + (size_t)3 * 256 * HDIM,
        w_hh + (size_t)4 * 256 * HDIM,
        b_ih + (size_t)4 * 256,
        b_hh + (size_t)4 * 256,
        seqp);
    fc_head<<<dim3(B_TOT / 256), dim3(256), 0, stream>>>(
        seqp, fc1_w, fc1_b, fc2_w, fc2_b, out);
}

// Round 15
// 6200.314 us; speedup vs baseline: 1.3764x; 1.3764x over previous
//
#include <hip/hip_runtime.h>
#include <math.h>

#define B_TOT 2048
#define T_LEN 512
#define HDIM 64
#define FC1 50
#define NSUP 514   // skew-2 pair: 512 + 2

typedef __bf16 bf16x8 __attribute__((ext_vector_type(8)));
typedef float f32x4 __attribute__((ext_vector_type(4)));
typedef unsigned int u32x4 __attribute__((ext_vector_type(4)));

// Fast transcendentals (no -ffast-math in harness; "/" would emit 12-inst IEEE div)
__device__ __forceinline__ float vrcp(float x) {
  float r; asm("v_rcp_f32 %0, %1" : "=v"(r) : "v"(x)); return r;
}
__device__ __forceinline__ float vexp2(float x) {
  float r; asm("v_exp_f32 %0, %1" : "=v"(r) : "v"(x)); return r;
}
__device__ __forceinline__ float sigm(float x) {
  return vrcp(1.0f + vexp2(x * -1.44269504088896340736f));
}
__device__ __forceinline__ float tanh_(float x) {
  return fmaf(2.0f, vrcp(1.0f + vexp2(x * -2.8853900817779268f)), -1.0f);
}

// lgkm-only barrier: LDS visibility without draining global queues.
#define BARRIER() asm volatile("s_waitcnt lgkmcnt(0)\n\ts_barrier" ::: "memory")
#define MFMA __builtin_amdgcn_mfma_f32_16x16x32_bf16

// Planar [16][64] bf16, 16B-chunk XOR swizzle: full-wave b128 = uniform 8 lanes/bank-group.
#define HADDR(row, chunk) (((row) << 6) + ((((chunk) ^ ((row) & 7))) << 3))

__device__ __forceinline__ void unpk(u32x4 p0, u32x4 p1, bf16x8* hi, bf16x8* lo) {
  u32x4 h, l;
  h[0] = __builtin_amdgcn_perm(p0[1], p0[0], 0x05040100u);
  h[1] = __builtin_amdgcn_perm(p0[3], p0[2], 0x05040100u);
  h[2] = __builtin_amdgcn_perm(p1[1], p1[0], 0x05040100u);
  h[3] = __builtin_amdgcn_perm(p1[3], p1[2], 0x05040100u);
  l[0] = __builtin_amdgcn_perm(p0[1], p0[0], 0x07060302u);
  l[1] = __builtin_amdgcn_perm(p0[3], p0[2], 0x07060302u);
  l[2] = __builtin_amdgcn_perm(p1[1], p1[0], 0x07060302u);
  l[3] = __builtin_amdgcn_perm(p1[3], p1[2], 0x07060302u);
  *hi = __builtin_bit_cast(bf16x8, h);
  *lo = __builtin_bit_cast(bf16x8, l);
}

// ---------- Skew-2 pair kernel, TWO independent 16-row tiles per block ------
// R15: block owns 32 batch rows = tiles U=0,1 with independent recurrences
// (separate cell/xacc/planes, SHARED weights). Per superstep each wave runs
// both tiles' chains; they are data-independent so the scheduler interleaves
// them -- tile1 issue fills tile0 latency stalls (ILP, not TLP: R14 showed
// extra blocks can't shorten a latency-bound chain; extra in-wave work can).
// KEEP __launch_bounds__(512,2): (512,4)/(1024,1) trigger weight remat
// (R12/R14: VGPR->64, FETCH 5+GB).  Numerics = R13 op order per tile.
#define SUPERT(N_, P_, U_)                                                     \
  {                                                                            \
    if (set == 0) {                                                            \
      if ((N_) < T_LEN) {                                                      \
        bf16x8 ahh0 = *(const bf16x8*)&Hhi[0][U_][1 - (P_)][HADDR(nn, cg)];    \
        bf16x8 ahh1 = *(const bf16x8*)&Hhi[0][U_][1 - (P_)][HADDR(nn, 4 + cg)];\
        bf16x8 ahl0 = *(const bf16x8*)&Hlo[0][U_][1 - (P_)][HADDR(nn, cg)];    \
        bf16x8 ahl1 = *(const bf16x8*)&Hlo[0][U_][1 - (P_)][HADDR(nn, 4 + cg)];\
        f32x4 accs[4];                                                         \
        _Pragma("unroll") for (int g = 0; g < 4; ++g) {                        \
          f32x4 a = xacc[U_][P_][g];                                           \
          a = MFMA(ahh0, bhh[g][0], a, 0, 0, 0);                               \
          a = MFMA(ahh1, bhh[g][1], a, 0, 0, 0);                               \
          a = MFMA(ahl0, bhh[g][0], a, 0, 0, 0);                               \
          a = MFMA(ahl1, bhh[g][1], a, 0, 0, 0);                               \
          accs[g] = a;                                                         \
        }                                                                      \
        _Pragma("unroll") for (int r = 0; r < 4; ++r) {                        \
          float iv = sigm(accs[0][r]);                                         \
          float fv = sigm(accs[1][r]);                                         \
          float gv = tanh_(accs[2][r]);                                        \
          float ov = sigm(accs[3][r]);                                         \
          cell[U_][r] = fv * cell[U_][r] + iv * gv;                            \
          float hv = ov * tanh_(cell[U_][r]);                                  \
          __bf16 h1 = (__bf16)hv;                                              \
          __bf16 h2 = (__bf16)(hv - (float)h1);                                \
          int mrow = 4 * cg + r;                                               \
          int ha = HADDR(mrow, uu >> 3) + (uu & 7);                            \
          Hhi[0][U_][P_][ha] = h1;                                             \
          Hlo[0][U_][P_][ha] = h2;                                             \
        }                                                                      \
      }                                                                        \
      /* tail: x-seed for t = N_+1 */                                         \
      if ((N_) + 1 < T_LEN) {                                                  \
        if (XIN) {                                                             \
          _Pragma("unroll") for (int g = 0; g < 4; ++g) {                      \
            f32x4 a;                                                           \
            _Pragma("unroll") for (int r = 0; r < 4; ++r)                      \
              a[r] = bias[g] + xw[g*3+0] * xr[U_][P_][r*3+0]                   \
                             + xw[g*3+1] * xr[U_][P_][r*3+1]                   \
                             + xw[g*3+2] * xr[U_][P_][r*3+2];                  \
            xacc[U_][1 - (P_)][g] = a;                                         \
          }                                                                    \
        } else {                                                               \
          bf16x8 xh0, xl0, xh1, xl1;                                           \
          unpk(xpk[U_][P_][0], xpk[U_][P_][1], &xh0, &xl0);                    \
          unpk(xpk[U_][P_][2], xpk[U_][P_][3], &xh1, &xl1);                    \
          _Pragma("unroll") for (int g = 0; g < 4; ++g) {                      \
            f32x4 a = {bias[g], bias[g], bias[g], bias[g]};                    \
            a = MFMA(xh0, bih[g][0], a, 0, 0, 0);                              \
            a = MFMA(xh1, bih[g][1], a, 0, 0, 0);                              \
            a = MFMA(xl0, bih[g][0], a, 0, 0, 0);                              \
            a = MFMA(xl1, bih[g][1], a, 0, 0, 0);                              \
            xacc[U_][1 - (P_)][g] = a;                                         \
          }                                                                    \
        }                                                                      \
      }                                                                        \
      {                                                                        \
        int tp = (N_) + 3; if (tp > T_LEN - 1) tp = T_LEN - 1;                 \
        if (XIN) {                                                             \
          _Pragma("unroll") for (int r = 0; r < 4; ++r)                        \
            _Pragma("unroll") for (int i = 0; i < 3; ++i)                      \
              xr[U_][P_][r*3+i] =                                              \
                  x_f32[((size_t)(bbase + (U_)*16 + 4*cg + r) * T_LEN + tp) * 3 + i]; \
        } else {                                                               \
          const unsigned int* px = seqp + xrowU[U_] + (size_t)tp * HDIM;       \
          xpk[U_][P_][0] = *(const u32x4*)(px + 8 * cg);                       \
          xpk[U_][P_][1] = *(const u32x4*)(px + 8 * cg + 4);                   \
          xpk[U_][P_][2] = *(const u32x4*)(px + 32 + 8 * cg);                  \
          xpk[U_][P_][3] = *(const u32x4*)(px + 32 + 8 * cg + 4);              \
        }                                                                      \
      }                                                                        \
    } else {                                                                   \
      if ((N_) >= 2) {                                                         \
        const int tl = (N_) - 2;                                               \
        bf16x8 ahh0 = *(const bf16x8*)&Hhi[1][U_][1 - (P_)][HADDR(nn, cg)];    \
        bf16x8 ahh1 = *(const bf16x8*)&Hhi[1][U_][1 - (P_)][HADDR(nn, 4 + cg)];\
        bf16x8 ahl0 = *(const bf16x8*)&Hlo[1][U_][1 - (P_)][HADDR(nn, cg)];    \
        bf16x8 ahl1 = *(const bf16x8*)&Hlo[1][U_][1 - (P_)][HADDR(nn, 4 + cg)];\
        f32x4 accs[4];                                                         \
        _Pragma("unroll") for (int g = 0; g < 4; ++g) {                        \
          f32x4 a = xacc[U_][P_][g];                                           \
          a = MFMA(ahh0, bhh[g][0], a, 0, 0, 0);                               \
          a = MFMA(ahh1, bhh[g][1], a, 0, 0, 0);                               \
          a = MFMA(ahl0, bhh[g][0], a, 0, 0, 0);                               \
          a = MFMA(ahl1, bhh[g][1], a, 0, 0, 0);                               \
          accs[g] = a;                                                         \
        }                                                                      \
        _Pragma("unroll") for (int r = 0; r < 4; ++r) {                        \
          float iv = sigm(accs[0][r]);                                         \
          float fv = sigm(accs[1][r]);                                         \
          float gv = tanh_(accs[2][r]);                                        \
          float ov = sigm(accs[3][r]);                                         \
          cell[U_][r] = fv * cell[U_][r] + iv * gv;                            \
          float hv = ov * tanh_(cell[U_][r]);                                  \
          __bf16 h1 = (__bf16)hv;                                              \
          __bf16 h2 = (__bf16)(hv - (float)h1);                                \
          int mrow = 4 * cg + r;                                               \
          int ha = HADDR(mrow, uu >> 3) + (uu & 7);                            \
          Hhi[1][U_][P_][ha] = h1;                                             \
          Hlo[1][U_][P_][ha] = h2;                                             \
          unsigned int hb = (unsigned int)__builtin_bit_cast(unsigned short, h1) \
                          | ((unsigned int)__builtin_bit_cast(unsigned short, h2) << 16); \
          seqp[((size_t)(bbase + (U_)*16 + mrow) * T_LEN + tl) * HDIM + uu] = hb; \
        }                                                                      \
      }                                                                        \
      /* tail: x-seed for t = N_-1 from upstream h0(N_-1), written pre-barrier */ \
      if ((N_) >= 1 && (N_) - 1 < T_LEN) {                                     \
        bf16x8 xh0 = *(const bf16x8*)&Hhi[0][U_][1 - (P_)][HADDR(nn, cg)];     \
        bf16x8 xh1 = *(const bf16x8*)&Hhi[0][U_][1 - (P_)][HADDR(nn, 4 + cg)]; \
        bf16x8 xl0 = *(const bf16x8*)&Hlo[0][U_][1 - (P_)][HADDR(nn, cg)];     \
        bf16x8 xl1 = *(const bf16x8*)&Hlo[0][U_][1 - (P_)][HADDR(nn, 4 + cg)]; \
        _Pragma("unroll") for (int g = 0; g < 4; ++g) {                        \
          f32x4 a = {bias[g], bias[g], bias[g], bias[g]};                      \
          a = MFMA(xh0, bih[g][0], a, 0, 0, 0);                                \
          a = MFMA(xh1, bih[g][1], a, 0, 0, 0);                                \
          a = MFMA(xl0, bih[g][0], a, 0, 0, 0);                                \
          a = MFMA(xl1, bih[g][1], a, 0, 0, 0);                                \
          xacc[U_][1 - (P_)][g] = a;                                           \
        }                                                                      \
      }                                                                        \
    }                                                                          \
  }

#define SUPERQ(N_, P_) { SUPERT(N_, P_, 0); SUPERT(N_, P_, 1); BARRIER(); }

template<int L0, bool XIN>
__global__ __launch_bounds__(512, 2)   // DO NOT raise: (512,4) causes weight remat
void lstm_pairq(const float* __restrict__ x_f32,
                const float* __restrict__ w_ih0,
                const float* __restrict__ w_ih_rest,
                const float* __restrict__ w_hh,
                const float* __restrict__ b_ih,
                const float* __restrict__ b_hh,
                unsigned int* __restrict__ seqp)
{
  const int tid  = threadIdx.x;
  const int lane = tid & 63;
  const int wv   = tid >> 6;
  const int set  = wv >> 2;       // 0,1 (wave-uniform)
  const int wq   = wv & 3;
  const int nn   = lane & 15;
  const int cg   = lane >> 4;
  const int bbase = blockIdx.x * 32;
  const int grow = 16 * wq + nn;
  const int uu   = grow;
  const int layer = L0 + set;

  __shared__ __align__(16) __bf16 Hhi[2][2][2][1024];  // [set][tile][parity] 16 KB
  __shared__ __align__(16) __bf16 Hlo[2][2][2][1024];  // 16 KB

  bf16x8 bhh[4][2];
#pragma unroll
  for (int g = 0; g < 4; ++g)
#pragma unroll
    for (int kk = 0; kk < 2; ++kk) {
      const float* wp = w_hh + (size_t)layer * 256 * 64
                      + (size_t)(64 * g + grow) * 64 + kk * 32 + 8 * cg;
      bf16x8 t;
#pragma unroll
      for (int e = 0; e < 8; ++e) t[e] = (__bf16)wp[e];
      bhh[g][kk] = t;
    }
  bf16x8 bih[4][2];
  float xw[12];
  if (XIN && set == 0) {
#pragma unroll
    for (int g = 0; g < 4; ++g)
#pragma unroll
      for (int i = 0; i < 3; ++i) xw[g * 3 + i] = w_ih0[(64 * g + grow) * 3 + i];
  } else {
    const float* wih_l = w_ih_rest + (size_t)(layer - 1) * 256 * 64;
#pragma unroll
    for (int g = 0; g < 4; ++g)
#pragma unroll
      for (int kk = 0; kk < 2; ++kk) {
        const float* wp = wih_l + (size_t)(64 * g + grow) * 64 + kk * 32 + 8 * cg;
        bf16x8 t;
#pragma unroll
        for (int e = 0; e < 8; ++e) t[e] = (__bf16)wp[e];
        bih[g][kk] = t;
      }
  }
  float bias[4];
#pragma unroll
  for (int g = 0; g < 4; ++g) {
    int row = layer * 256 + 64 * g + grow;
    bias[g] = b_ih[row] + b_hh[row];
  }

  for (int q = tid; q < 8 * 1024; q += 512) {
    ((__bf16*)Hhi)[q] = (__bf16)0.f;
    ((__bf16*)Hlo)[q] = (__bf16)0.f;
  }

  float cell[2][4] = {{0.f,0.f,0.f,0.f},{0.f,0.f,0.f,0.f}};
  size_t xrowU[2];
  xrowU[0] = (size_t)(bbase + nn) * T_LEN * HDIM;
  xrowU[1] = (size_t)(bbase + 16 + nn) * T_LEN * HDIM;

  f32x4 xacc[2][2][4];   // [tile][parity][gate] — all literal indices
  float xr[2][2][12];
  u32x4 xpk[2][2][4];

  if (set == 0) {
#pragma unroll
    for (int U = 0; U < 2; ++U) {
      if (XIN) {
        float x0[12];
#pragma unroll
        for (int r = 0; r < 4; ++r)
#pragma unroll
          for (int i = 0; i < 3; ++i)
            x0[r*3+i] = x_f32[((size_t)(bbase + U*16 + 4*cg + r) * T_LEN + 0) * 3 + i];
#pragma unroll
        for (int g = 0; g < 4; ++g) {
          f32x4 a;
#pragma unroll
          for (int r = 0; r < 4; ++r)
            a[r] = bias[g] + xw[g*3+0]*x0[r*3+0] + xw[g*3+1]*x0[r*3+1] + xw[g*3+2]*x0[r*3+2];
          xacc[U][0][g] = a;
        }
#pragma unroll
        for (int p = 0; p < 2; ++p)
#pragma unroll
          for (int r = 0; r < 4; ++r)
#pragma unroll
            for (int i = 0; i < 3; ++i)
              xr[U][p][r*3+i] = x_f32[((size_t)(bbase + U*16 + 4*cg + r) * T_LEN + (p + 1)) * 3 + i];
      } else {
        const unsigned int* px = seqp + xrowU[U];
        u32x4 q0 = *(const u32x4*)(px + 8 * cg);
        u32x4 q1 = *(const u32x4*)(px + 8 * cg + 4);
        u32x4 q2 = *(const u32x4*)(px + 32 + 8 * cg);
        u32x4 q3 = *(const u32x4*)(px + 32 + 8 * cg + 4);
        bf16x8 xh0, xl0, xh1, xl1;
        unpk(q0, q1, &xh0, &xl0);
        unpk(q2, q3, &xh1, &xl1);
#pragma unroll
        for (int g = 0; g < 4; ++g) {
          f32x4 a = {bias[g], bias[g], bias[g], bias[g]};
          a = MFMA(xh0, bih[g][0], a, 0, 0, 0);
          a = MFMA(xh1, bih[g][1], a, 0, 0, 0);
          a = MFMA(xl0, bih[g][0], a, 0, 0, 0);
          a = MFMA(xl1, bih[g][1], a, 0, 0, 0);
          xacc[U][0][g] = a;
        }
#pragma unroll
        for (int p = 0; p < 2; ++p) {
          const unsigned int* pq = seqp + xrowU[U] + (size_t)(p + 1) * HDIM;
          xpk[U][p][0] = *(const u32x4*)(pq + 8 * cg);
          xpk[U][p][1] = *(const u32x4*)(pq + 8 * cg + 4);
          xpk[U][p][2] = *(const u32x4*)(pq + 32 + 8 * cg);
          xpk[U][p][3] = *(const u32x4*)(pq + 32 + 8 * cg + 4);
        }
      }
    }
  }
  __syncthreads();

  for (int n = 0; n < NSUP; n += 2) {
    SUPERQ(n,     0);
    SUPERQ(n + 1, 1);
  }
}

// -------------- Single-layer kernel, two 16-row tiles (layer 4) -------------
#define STEPT(T0, P, U_)                                                       \
  {                                                                            \
    if (isA) {                                                                 \
      bf16x8 ahh0 = *(const bf16x8*)&h_hi[U_][P][HADDR(nn, cg)];               \
      bf16x8 ahh1 = *(const bf16x8*)&h_hi[U_][P][HADDR(nn, 4 + cg)];           \
      bf16x8 ahl0 = *(const bf16x8*)&h_lo[U_][P][HADDR(nn, cg)];               \
      bf16x8 ahl1 = *(const bf16x8*)&h_lo[U_][P][HADDR(nn, 4 + cg)];           \
      f32x4 accs[4];                                                           \
      _Pragma("unroll")                                                        \
      for (int g = 0; g < 4; ++g) {                                            \
        f32x4 a = accx[U_][P][g][wq * 64 + lane];                              \
        a = MFMA(ahh0, bhh[g][0], a, 0, 0, 0);                                 \
        a = MFMA(ahh1, bhh[g][1], a, 0, 0, 0);                                 \
        a = MFMA(ahl0, bhh[g][0], a, 0, 0, 0);                                 \
        a = MFMA(ahl1, bhh[g][1], a, 0, 0, 0);                                 \
        accs[g] = a;                                                           \
      }                                                                        \
      _Pragma("unroll")                                                        \
      for (int r = 0; r < 4; ++r) {                                            \
        float iv = sigm(accs[0][r]);                                           \
        float fv = sigm(accs[1][r]);                                           \
        float gv = tanh_(accs[2][r]);                                          \
        float ov = sigm(accs[3][r]);                                           \
        cell[U_][r] = fv * cell[U_][r] + iv * gv;                              \
        float hv = ov * tanh_(cell[U_][r]);                                    \
        __bf16 h1 = (__bf16)hv;                                                \
        __bf16 h2 = (__bf16)(hv - (float)h1);                                  \
        int mrow = 4 * cg + r;                                                 \
        int ha = HADDR(mrow, uu >> 3) + (uu & 7);                              \
        h_hi[U_][1 - (P)][ha] = h1;                                            \
        h_lo[U_][1 - (P)][ha] = h2;                                            \
      }                                                                        \
    } else {                                                                   \
      if ((T0) > 0) {                                                          \
        _Pragma("unroll")                                                      \
        for (int r = 0; r < 4; ++r) {                                          \
          int mrow = 4 * cg + r;                                               \
          int ha = HADDR(mrow, uu >> 3) + (uu & 7);                            \
          unsigned int hb =                                                    \
              (unsigned int)__builtin_bit_cast(unsigned short, h_hi[U_][P][ha])\
            | ((unsigned int)__builtin_bit_cast(unsigned short, h_lo[U_][P][ha]) << 16); \
          seqp[((size_t)(bbase + (U_)*16 + mrow) * T_LEN + (T0) - 1) * HDIM + uu] = hb; \
        }                                                                      \
      }                                                                        \
      if ((T0) + 1 < T_LEN) {                                                  \
        bf16x8 xh0, xl0, xh1, xl1;                                             \
        unpk(xpk[U_][P][0], xpk[U_][P][1], &xh0, &xl0);                        \
        unpk(xpk[U_][P][2], xpk[U_][P][3], &xh1, &xl1);                        \
        _Pragma("unroll")                                                      \
        for (int g = 0; g < 4; ++g) {                                          \
          f32x4 a = {bias[g], bias[g], bias[g], bias[g]};                      \
          a = MFMA(xh0, bih[g][0], a, 0, 0, 0);                                \
          a = MFMA(xh1, bih[g][1], a, 0, 0, 0);                                \
          a = MFMA(xl0, bih[g][0], a, 0, 0, 0);                                \
          a = MFMA(xl1, bih[g][1], a, 0, 0, 0);                                \
          accx[U_][1 - (P)][g][wq * 64 + lane] = a;                            \
        }                                                                      \
      }                                                                        \
      {                                                                        \
        int tp = (T0) + 3; if (tp >= T_LEN) tp = T_LEN - 1;                    \
        const unsigned int* px = seqp + xrowU[U_] + (size_t)tp * HDIM;         \
        xpk[U_][P][0] = *(const u32x4*)(px + 8 * cg);                          \
        xpk[U_][P][1] = *(const u32x4*)(px + 8 * cg + 4);                      \
        xpk[U_][P][2] = *(const u32x4*)(px + 32 + 8 * cg);                     \
        xpk[U_][P][3] = *(const u32x4*)(px + 32 + 8 * cg + 4);                 \
      }                                                                        \
    }                                                                          \
  }

#define STEP2(T0, P) { STEPT(T0, P, 0); STEPT(T0, P, 1); BARRIER(); }

__global__ __launch_bounds__(512, 2)
void lstm_single(const float* __restrict__ w_ih,
                 const float* __restrict__ w_hh,
                 const float* __restrict__ b_ih,
                 const float* __restrict__ b_hh,
                 unsigned int* seqp)
{
    const int tid  = threadIdx.x;
    const int lane = tid & 63;
    const int wv   = tid >> 6;
    const bool isA = (wv < 4);
    const int wq   = wv & 3;
    const int nn   = lane & 15;
    const int cg   = lane >> 4;
    const int bbase = blockIdx.x * 32;
    const int grow = 16 * wq + nn;
    const int uu   = grow;

    __shared__ __align__(16) __bf16 h_hi[2][2][1024];       // [tile][parity] 8 KB
    __shared__ __align__(16) __bf16 h_lo[2][2][1024];       // 8 KB
    __shared__ __align__(16) f32x4 accx[2][2][4][256];      // 64 KB

    bf16x8 bhh[4][2];
    bf16x8 bih[4][2];
    float bias[4];
    if (isA) {
#pragma unroll
      for (int g = 0; g < 4; ++g)
#pragma unroll
        for (int kk = 0; kk < 2; ++kk) {
          const float* wp = w_hh + (size_t)(64 * g + grow) * 64 + kk * 32 + 8 * cg;
          bf16x8 t;
#pragma unroll
          for (int e = 0; e < 8; ++e) t[e] = (__bf16)wp[e];
          bhh[g][kk] = t;
        }
    } else {
#pragma unroll
      for (int g = 0; g < 4; ++g) {
        int row = 64 * g + grow;
        bias[g] = b_ih[row] + b_hh[row];
      }
#pragma unroll
      for (int g = 0; g < 4; ++g)
#pragma unroll
        for (int kk = 0; kk < 2; ++kk) {
          const float* wp = w_ih + (size_t)(64 * g + grow) * 64 + kk * 32 + 8 * cg;
          bf16x8 t;
#pragma unroll
          for (int e = 0; e < 8; ++e) t[e] = (__bf16)wp[e];
          bih[g][kk] = t;
        }
    }

    for (int q = tid; q < 4 * 1024; q += 512) {
      ((__bf16*)h_hi)[q] = (__bf16)0.f;
      ((__bf16*)h_lo)[q] = (__bf16)0.f;
    }

    float cell[2][4] = {{0.f,0.f,0.f,0.f},{0.f,0.f,0.f,0.f}};
    size_t xrowU[2];
    xrowU[0] = (size_t)(bbase + nn) * T_LEN * HDIM;
    xrowU[1] = (size_t)(bbase + 16 + nn) * T_LEN * HDIM;
    u32x4 xpk[2][2][4];

    if (!isA) {
#pragma unroll
      for (int U = 0; U < 2; ++U) {
        const unsigned int* px = seqp + xrowU[U];
        u32x4 q0 = *(const u32x4*)(px + 8 * cg);
        u32x4 q1 = *(const u32x4*)(px + 8 * cg + 4);
        u32x4 q2 = *(const u32x4*)(px + 32 + 8 * cg);
        u32x4 q3 = *(const u32x4*)(px + 32 + 8 * cg + 4);
        bf16x8 xh0, xl0, xh1, xl1;
        unpk(q0, q1, &xh0, &xl0);
        unpk(q2, q3, &xh1, &xl1);
#pragma unroll
        for (int g = 0; g < 4; ++g) {
          f32x4 a = {bias[g], bias[g], bias[g], bias[g]};
          a = MFMA(xh0, bih[g][0], a, 0, 0, 0);
          a = MFMA(xh1, bih[g][1], a, 0, 0, 0);
          a = MFMA(xl0, bih[g][0], a, 0, 0, 0);
          a = MFMA(xl1, bih[g][1], a, 0, 0, 0);
          accx[U][0][g][wq * 64 + lane] = a;
        }
#pragma unroll
        for (int p = 0; p < 2; ++p) {
          const unsigned int* pq = seqp + xrowU[U] + (size_t)(p + 1) * HDIM;
          xpk[U][p][0] = *(const u32x4*)(pq + 8 * cg);
          xpk[U][p][1] = *(const u32x4*)(pq + 8 * cg + 4);
          xpk[U][p][2] = *(const u32x4*)(pq + 32 + 8 * cg);
          xpk[U][p][3] = *(const u32x4*)(pq + 32 + 8 * cg + 4);
        }
      }
    }
    __syncthreads();

    if (isA) __builtin_amdgcn_s_setprio(1);
    for (int t = 0; t < T_LEN; t += 2) {
      STEP2(t, 0);
      STEP2(t + 1, 1);
    }
    if (isA) __builtin_amdgcn_s_setprio(0);

    if (!isA) {
#pragma unroll
      for (int U = 0; U < 2; ++U)
#pragma unroll
      for (int r = 0; r < 4; ++r) {
        int mrow = 4 * cg + r;
        int ha = HADDR(mrow, uu >> 3) + (uu & 7);
        unsigned int hb =
            (unsigned int)__builtin_bit_cast(unsigned short, h_hi[U][0][ha])
          | ((unsigned int)__builtin_bit_cast(unsigned short, h_lo[U][0][ha]) << 16);
        seqp[((size_t)(bbase + U*16 + mrow) * T_LEN + (T_LEN - 1)) * HDIM + uu] = hb;
      }
    }
}

// FC head: out[b] = fc2_b + fc2_w . relu(fc1_b + fc1_w . h_T[b])
__global__ __launch_bounds__(256, 1)
void fc_head(const unsigned int* __restrict__ seqp,
             const float* __restrict__ fc1_w, const float* __restrict__ fc1_b,
             const float* __restrict__ fc2_w, const float* __restrict__ fc2_b,
             float* __restrict__ out)
{
    __shared__ float w1[FC1 * HDIM];
    __shared__ float b1[FC1];
    __shared__ float w2[FC1];
    const int tid = threadIdx.x;
    for (int i = tid; i < FC1 * HDIM; i += 256) w1[i] = fc1_w[i];
    if (tid < FC1) { b1[tid] = fc1_b[tid]; w2[tid] = fc2_w[tid]; }
    __syncthreads();

    const int b = blockIdx.x * 256 + tid;
    const size_t base = ((size_t)b * T_LEN + (T_LEN - 1)) * HDIM;
    float h[HDIM];
#pragma unroll
    for (int q = 0; q < HDIM; ++q) {
      unsigned int v = seqp[base + q];
      float hi = (float)__builtin_bit_cast(__bf16, (unsigned short)(v & 0xffffu));
      float lo = (float)__builtin_bit_cast(__bf16, (unsigned short)(v >> 16));
      h[q] = hi + lo;
    }
    float acc2 = fc2_b[0];
    for (int m = 0; m < FC1; ++m) {
      float a = b1[m];
#pragma unroll
      for (int q = 0; q < HDIM; ++q) a += w1[m * HDIM + q] * h[q];
      acc2 += w2[m] * fmaxf(a, 0.0f);
    }
    out[b] = acc2;
}

extern "C" void kernel_launch(void* const* d_in, const int* in_sizes, int n_in,
                              void* d_out, int out_size, void* d_ws, size_t ws_size,
                              hipStream_t stream) {
    const float* x         = (const float*)d_in[0];
    const float* w_ih0     = (const float*)d_in[1];
    const float* w_ih_rest = (const float*)d_in[2];
    const float* w_hh      = (const float*)d_in[3];
    const float* b_ih      = (const float*)d_in[4];
    const float* b_hh      = (const float*)d_in[5];
    const float* fc1_w     = (const float*)d_in[6];
    const float* fc1_b     = (const float*)d_in[7];
    const float* fc2_w     = (const float*)d_in[8];
    const float* fc2_b     = (const float*)d_in[9];
    float* out = (float*)d_out;

    unsigned int* seqp = (unsigned int*)d_ws;   // [B,T,64] packed = 256 MiB

    // layers 0+1, skew-2 pair, 2x16-row tiles (64 blocks); writes seq1
    lstm_pairq<0, true><<<dim3(B_TOT / 32), dim3(512), 0, stream>>>(
        x, w_ih0, w_ih_rest, w_hh, b_ih, b_hh, seqp);
    // layers 2+3; reads seq1 / writes seq3 in-place (gap >= 5)
    lstm_pairq<2, false><<<dim3(B_TOT / 32), dim3(512), 0, stream>>>(
        x, w_ih0, w_ih_rest, w_hh, b_ih, b_hh, seqp);
    // layer 4; reads seq3 / writes seq4 in-place (gap 4)
    lstm_single<<<dim3(B_TOT / 32), dim3(512), 0, stream>>>(
        w_ih_rest + (size_t)3 * 256 * HDIM,
        w_hh + (size_t)4 * 256 * HDIM,
        b_ih + (size_t)4 * 256,
        b_hh + (size_t)4 * 256,
        seqp);
    fc_head<<<dim3(B_TOT / 256), dim3(256), 0, stream>>>(
        seqp, fc1_w, fc1_b, fc2_w, fc2_b, out);
}

// Round 16
// 1620.746 us; speedup vs baseline: 5.2655x; 3.8256x over previous
//
#include <hip/hip_runtime.h>
#include <math.h>

#define B_TOT 2048
#define T_LEN 512
#define HDIM 64
#define FC1 50
#define NSUP 514   // skew-2 pair: 512 + 2

typedef __bf16 bf16x8 __attribute__((ext_vector_type(8)));
typedef float f32x4 __attribute__((ext_vector_type(4)));
typedef unsigned int u32x4 __attribute__((ext_vector_type(4)));

// Fast transcendentals (no -ffast-math in harness; "/" would emit 12-inst IEEE div)
__device__ __forceinline__ float vrcp(float x) {
  float r; asm("v_rcp_f32 %0, %1" : "=v"(r) : "v"(x)); return r;
}
__device__ __forceinline__ float vexp2(float x) {
  float r; asm("v_exp_f32 %0, %1" : "=v"(r) : "v"(x)); return r;
}
__device__ __forceinline__ float sigm(float x) {
  return vrcp(1.0f + vexp2(x * -1.44269504088896340736f));
}
__device__ __forceinline__ float tanh_(float x) {
  return fmaf(2.0f, vrcp(1.0f + vexp2(x * -2.8853900817779268f)), -1.0f);
}

// lgkm-only barrier: LDS visibility without draining global queues.
#define BARRIER() asm volatile("s_waitcnt lgkmcnt(0)\n\ts_barrier" ::: "memory")
#define MFMA __builtin_amdgcn_mfma_f32_16x16x32_bf16

// Planar [16][64] bf16, 16B-chunk XOR swizzle: full-wave b128 = uniform 8 lanes/bank-group.
#define HADDR(row, chunk) (((row) << 6) + ((((chunk) ^ ((row) & 7))) << 3))

__device__ __forceinline__ void unpk(u32x4 p0, u32x4 p1, bf16x8* hi, bf16x8* lo) {
  u32x4 h, l;
  h[0] = __builtin_amdgcn_perm(p0[1], p0[0], 0x05040100u);
  h[1] = __builtin_amdgcn_perm(p0[3], p0[2], 0x05040100u);
  h[2] = __builtin_amdgcn_perm(p1[1], p1[0], 0x05040100u);
  h[3] = __builtin_amdgcn_perm(p1[3], p1[2], 0x05040100u);
  l[0] = __builtin_amdgcn_perm(p0[1], p0[0], 0x07060302u);
  l[1] = __builtin_amdgcn_perm(p0[3], p0[2], 0x07060302u);
  l[2] = __builtin_amdgcn_perm(p1[1], p1[0], 0x07060302u);
  l[3] = __builtin_amdgcn_perm(p1[3], p1[2], 0x07060302u);
  *hi = __builtin_bit_cast(bf16x8, h);
  *lo = __builtin_bit_cast(bf16x8, l);
}

// ---------- Skew-2 pair kernel (R13 base + R16 chain polish) ----------------
// 512 thr = 8 waves: set = wv>>2 (layer L0+set), 4 waves each.
// R16 changes vs R13 (proven 1578us):
//  (1) 4-chained MFMAs -> two 2-chains (hi seeded by xacc, lo seeded by 0)
//      + one v_add: critical path loses ~2 MFMA latencies. (f32 re-assoc only)
//  (2) set1 runs its tail BEFORE its chain (phase-desync of the two sets'
//      pipe usage; tail data was written before the PREVIOUS barrier - safe).
//  (3) set1's global stores collected after the r-loop.
// DO NOT raise __launch_bounds__ past (512,2): (512,4)/(1024,*) trigger
// weight remat (R12/R14/R15: VGPR collapse, FETCH x40, 2-5x slowdowns).
#define SUPERQ(N_, P_)                                                         \
  {                                                                            \
    if (set == 0) {                                                            \
      if ((N_) < T_LEN) {                                                      \
        bf16x8 ahh0 = *(const bf16x8*)&Hhi[0][1 - (P_)][HADDR(nn, cg)];        \
        bf16x8 ahh1 = *(const bf16x8*)&Hhi[0][1 - (P_)][HADDR(nn, 4 + cg)];    \
        bf16x8 ahl0 = *(const bf16x8*)&Hlo[0][1 - (P_)][HADDR(nn, cg)];        \
        bf16x8 ahl1 = *(const bf16x8*)&Hlo[0][1 - (P_)][HADDR(nn, 4 + cg)];    \
        f32x4 accs[4];                                                         \
        _Pragma("unroll") for (int g = 0; g < 4; ++g) {                        \
          f32x4 a0 = xacc[P_][g];                                              \
          f32x4 a1 = {0.f, 0.f, 0.f, 0.f};                                     \
          a0 = MFMA(ahh0, bhh[g][0], a0, 0, 0, 0);                             \
          a1 = MFMA(ahl0, bhh[g][0], a1, 0, 0, 0);                             \
          a0 = MFMA(ahh1, bhh[g][1], a0, 0, 0, 0);                             \
          a1 = MFMA(ahl1, bhh[g][1], a1, 0, 0, 0);                             \
          accs[g] = a0 + a1;                                                   \
        }                                                                      \
        _Pragma("unroll") for (int r = 0; r < 4; ++r) {                        \
          float iv = sigm(accs[0][r]);                                         \
          float fv = sigm(accs[1][r]);                                         \
          float gv = tanh_(accs[2][r]);                                        \
          float ov = sigm(accs[3][r]);                                         \
          cell[r] = fv * cell[r] + iv * gv;                                    \
          float hv = ov * tanh_(cell[r]);                                      \
          __bf16 h1 = (__bf16)hv;                                              \
          __bf16 h2 = (__bf16)(hv - (float)h1);                                \
          int mrow = 4 * cg + r;                                               \
          int ha = HADDR(mrow, uu >> 3) + (uu & 7);                            \
          Hhi[0][P_][ha] = h1;                                                 \
          Hlo[0][P_][ha] = h2;                                                 \
        }                                                                      \
      }                                                                        \
      /* tail: x-seed for t = N_+1 */                                         \
      if ((N_) + 1 < T_LEN) {                                                  \
        if (XIN) {                                                             \
          _Pragma("unroll") for (int g = 0; g < 4; ++g) {                      \
            f32x4 a;                                                           \
            _Pragma("unroll") for (int r = 0; r < 4; ++r)                      \
              a[r] = bias[g] + xw[g*3+0] * xr[P_][r*3+0]                       \
                             + xw[g*3+1] * xr[P_][r*3+1]                       \
                             + xw[g*3+2] * xr[P_][r*3+2];                      \
            xacc[1 - (P_)][g] = a;                                             \
          }                                                                    \
        } else {                                                               \
          bf16x8 xh0, xl0, xh1, xl1;                                           \
          unpk(xpk[P_][0], xpk[P_][1], &xh0, &xl0);                            \
          unpk(xpk[P_][2], xpk[P_][3], &xh1, &xl1);                            \
          _Pragma("unroll") for (int g = 0; g < 4; ++g) {                      \
            f32x4 a = {bias[g], bias[g], bias[g], bias[g]};                    \
            a = MFMA(xh0, bih[g][0], a, 0, 0, 0);                              \
            a = MFMA(xh1, bih[g][1], a, 0, 0, 0);                              \
            a = MFMA(xl0, bih[g][0], a, 0, 0, 0);                              \
            a = MFMA(xl1, bih[g][1], a, 0, 0, 0);                              \
            xacc[1 - (P_)][g] = a;                                             \
          }                                                                    \
        }                                                                      \
      }                                                                        \
      {                                                                        \
        int tp = (N_) + 3; if (tp > T_LEN - 1) tp = T_LEN - 1;                 \
        if (XIN) {                                                             \
          _Pragma("unroll") for (int r = 0; r < 4; ++r)                        \
            _Pragma("unroll") for (int i = 0; i < 3; ++i)                      \
              xr[P_][r*3+i] =                                                  \
                  x_f32[((size_t)(bbase + 4*cg + r) * T_LEN + tp) * 3 + i];    \
        } else {                                                               \
          const unsigned int* px = seqp + xrow + (size_t)tp * HDIM;            \
          xpk[P_][0] = *(const u32x4*)(px + 8 * cg);                           \
          xpk[P_][1] = *(const u32x4*)(px + 8 * cg + 4);                       \
          xpk[P_][2] = *(const u32x4*)(px + 32 + 8 * cg);                      \
          xpk[P_][3] = *(const u32x4*)(px + 32 + 8 * cg + 4);                  \
        }                                                                      \
      }                                                                        \
    } else {                                                                   \
      /* set1 TAIL FIRST (phase desync): x-seed for t = N_-1 from h0(N_-1),  */\
      /* written by set0 before the PREVIOUS barrier -> no dependency on the */\
      /* current window. */                                                    \
      if ((N_) >= 1 && (N_) - 1 < T_LEN) {                                     \
        bf16x8 xh0 = *(const bf16x8*)&Hhi[0][1 - (P_)][HADDR(nn, cg)];         \
        bf16x8 xh1 = *(const bf16x8*)&Hhi[0][1 - (P_)][HADDR(nn, 4 + cg)];     \
        bf16x8 xl0 = *(const bf16x8*)&Hlo[0][1 - (P_)][HADDR(nn, cg)];         \
        bf16x8 xl1 = *(const bf16x8*)&Hlo[0][1 - (P_)][HADDR(nn, 4 + cg)];     \
        _Pragma("unroll") for (int g = 0; g < 4; ++g) {                        \
          f32x4 a = {bias[g], bias[g], bias[g], bias[g]};                      \
          a = MFMA(xh0, bih[g][0], a, 0, 0, 0);                                \
          a = MFMA(xh1, bih[g][1], a, 0, 0, 0);                                \
          a = MFMA(xl0, bih[g][0], a, 0, 0, 0);                                \
          a = MFMA(xl1, bih[g][1], a, 0, 0, 0);                                \
          xacc[1 - (P_)][g] = a;                                               \
        }                                                                      \
      }                                                                        \
      if ((N_) >= 2) {                                                         \
        const int tl = (N_) - 2;                                               \
        bf16x8 ahh0 = *(const bf16x8*)&Hhi[1][1 - (P_)][HADDR(nn, cg)];        \
        bf16x8 ahh1 = *(const bf16x8*)&Hhi[1][1 - (P_)][HADDR(nn, 4 + cg)];    \
        bf16x8 ahl0 = *(const bf16x8*)&Hlo[1][1 - (P_)][HADDR(nn, cg)];        \
        bf16x8 ahl1 = *(const bf16x8*)&Hlo[1][1 - (P_)][HADDR(nn, 4 + cg)];    \
        f32x4 accs[4];                                                         \
        _Pragma("unroll") for (int g = 0; g < 4; ++g) {                        \
          f32x4 a0 = xacc[P_][g];                                              \
          f32x4 a1 = {0.f, 0.f, 0.f, 0.f};                                     \
          a0 = MFMA(ahh0, bhh[g][0], a0, 0, 0, 0);                             \
          a1 = MFMA(ahl0, bhh[g][0], a1, 0, 0, 0);                             \
          a0 = MFMA(ahh1, bhh[g][1], a0, 0, 0, 0);                             \
          a1 = MFMA(ahl1, bhh[g][1], a1, 0, 0, 0);                             \
          accs[g] = a0 + a1;                                                   \
        }                                                                      \
        unsigned int hbv[4];                                                   \
        _Pragma("unroll") for (int r = 0; r < 4; ++r) {                        \
          float iv = sigm(accs[0][r]);                                         \
          float fv = sigm(accs[1][r]);                                         \
          float gv = tanh_(accs[2][r]);                                        \
          float ov = sigm(accs[3][r]);                                         \
          cell[r] = fv * cell[r] + iv * gv;                                    \
          float hv = ov * tanh_(cell[r]);                                      \
          __bf16 h1 = (__bf16)hv;                                              \
          __bf16 h2 = (__bf16)(hv - (float)h1);                                \
          int mrow = 4 * cg + r;                                               \
          int ha = HADDR(mrow, uu >> 3) + (uu & 7);                            \
          Hhi[1][P_][ha] = h1;                                                 \
          Hlo[1][P_][ha] = h2;                                                 \
          hbv[r] = (unsigned int)__builtin_bit_cast(unsigned short, h1)        \
                 | ((unsigned int)__builtin_bit_cast(unsigned short, h2) << 16); \
        }                                                                      \
        _Pragma("unroll") for (int r = 0; r < 4; ++r) {                        \
          int mrow = 4 * cg + r;                                               \
          seqp[((size_t)(bbase + mrow) * T_LEN + tl) * HDIM + uu] = hbv[r];    \
        }                                                                      \
      }                                                                        \
    }                                                                          \
    BARRIER();                                                                 \
  }

template<int L0, bool XIN>
__global__ __launch_bounds__(512, 2)   // DO NOT raise (remat hazard: R12/R14/R15)
void lstm_pairq(const float* __restrict__ x_f32,
                const float* __restrict__ w_ih0,
                const float* __restrict__ w_ih_rest,
                const float* __restrict__ w_hh,
                const float* __restrict__ b_ih,
                const float* __restrict__ b_hh,
                unsigned int* __restrict__ seqp)
{
  const int tid  = threadIdx.x;
  const int lane = tid & 63;
  const int wv   = tid >> 6;
  const int set  = wv >> 2;       // 0,1 (wave-uniform)
  const int wq   = wv & 3;
  const int nn   = lane & 15;
  const int cg   = lane >> 4;
  const int bbase = blockIdx.x * 16;
  const int grow = 16 * wq + nn;
  const int uu   = grow;
  const int layer = L0 + set;

  __shared__ __align__(16) __bf16 Hhi[2][2][1024];  // 8 KB
  __shared__ __align__(16) __bf16 Hlo[2][2][1024];  // 8 KB

  bf16x8 bhh[4][2];
#pragma unroll
  for (int g = 0; g < 4; ++g)
#pragma unroll
    for (int kk = 0; kk < 2; ++kk) {
      const float* wp = w_hh + (size_t)layer * 256 * 64
                      + (size_t)(64 * g + grow) * 64 + kk * 32 + 8 * cg;
      bf16x8 t;
#pragma unroll
      for (int e = 0; e < 8; ++e) t[e] = (__bf16)wp[e];
      bhh[g][kk] = t;
    }
  bf16x8 bih[4][2];
  float xw[12];
  if (XIN && set == 0) {
#pragma unroll
    for (int g = 0; g < 4; ++g)
#pragma unroll
      for (int i = 0; i < 3; ++i) xw[g * 3 + i] = w_ih0[(64 * g + grow) * 3 + i];
  } else {
    const float* wih_l = w_ih_rest + (size_t)(layer - 1) * 256 * 64;
#pragma unroll
    for (int g = 0; g < 4; ++g)
#pragma unroll
      for (int kk = 0; kk < 2; ++kk) {
        const float* wp = wih_l + (size_t)(64 * g + grow) * 64 + kk * 32 + 8 * cg;
        bf16x8 t;
#pragma unroll
        for (int e = 0; e < 8; ++e) t[e] = (__bf16)wp[e];
        bih[g][kk] = t;
      }
  }
  float bias[4];
#pragma unroll
  for (int g = 0; g < 4; ++g) {
    int row = layer * 256 + 64 * g + grow;
    bias[g] = b_ih[row] + b_hh[row];
  }

  for (int q = tid; q < 4 * 1024; q += 512) {
    ((__bf16*)Hhi)[q] = (__bf16)0.f;
    ((__bf16*)Hlo)[q] = (__bf16)0.f;
  }

  float cell[4] = {0.f, 0.f, 0.f, 0.f};
  const size_t xrow = (size_t)(bbase + nn) * T_LEN * HDIM;

  f32x4 xacc[2][4];   // register x-seed, parity-indexed (macro-literal P_ only)
  float xr[2][12];    // set0 XIN queue
  u32x4 xpk[2][4];    // set0 GIN queue

  if (set == 0) {
    if (XIN) {
      float x0[12];
#pragma unroll
      for (int r = 0; r < 4; ++r)
#pragma unroll
        for (int i = 0; i < 3; ++i)
          x0[r*3+i] = x_f32[((size_t)(bbase + 4*cg + r) * T_LEN + 0) * 3 + i];
#pragma unroll
      for (int g = 0; g < 4; ++g) {
        f32x4 a;
#pragma unroll
        for (int r = 0; r < 4; ++r)
          a[r] = bias[g] + xw[g*3+0]*x0[r*3+0] + xw[g*3+1]*x0[r*3+1] + xw[g*3+2]*x0[r*3+2];
        xacc[0][g] = a;
      }
#pragma unroll
      for (int p = 0; p < 2; ++p)
#pragma unroll
        for (int r = 0; r < 4; ++r)
#pragma unroll
          for (int i = 0; i < 3; ++i)
            xr[p][r*3+i] = x_f32[((size_t)(bbase + 4*cg + r) * T_LEN + (p + 1)) * 3 + i];
    } else {
      const unsigned int* px = seqp + xrow;
      u32x4 q0 = *(const u32x4*)(px + 8 * cg);
      u32x4 q1 = *(const u32x4*)(px + 8 * cg + 4);
      u32x4 q2 = *(const u32x4*)(px + 32 + 8 * cg);
      u32x4 q3 = *(const u32x4*)(px + 32 + 8 * cg + 4);
      bf16x8 xh0, xl0, xh1, xl1;
      unpk(q0, q1, &xh0, &xl0);
      unpk(q2, q3, &xh1, &xl1);
#pragma unroll
      for (int g = 0; g < 4; ++g) {
        f32x4 a = {bias[g], bias[g], bias[g], bias[g]};
        a = MFMA(xh0, bih[g][0], a, 0, 0, 0);
        a = MFMA(xh1, bih[g][1], a, 0, 0, 0);
        a = MFMA(xl0, bih[g][0], a, 0, 0, 0);
        a = MFMA(xl1, bih[g][1], a, 0, 0, 0);
        xacc[0][g] = a;
      }
#pragma unroll
      for (int p = 0; p < 2; ++p) {
        const unsigned int* pq = seqp + xrow + (size_t)(p + 1) * HDIM;
        xpk[p][0] = *(const u32x4*)(pq + 8 * cg);
        xpk[p][1] = *(const u32x4*)(pq + 8 * cg + 4);
        xpk[p][2] = *(const u32x4*)(pq + 32 + 8 * cg);
        xpk[p][3] = *(const u32x4*)(pq + 32 + 8 * cg + 4);
      }
    }
  }
  __syncthreads();

  for (int n = 0; n < NSUP; n += 2) {
    SUPERQ(n,     0);
    SUPERQ(n + 1, 1);
  }
}

// -------------- Single-layer kernel (R9/R11-proven, layer 4) ---------------
#define STEP(T0, P)                                                            \
  {                                                                            \
    if (isA) {                                                                 \
      bf16x8 ahh0 = *(const bf16x8*)&h_hi[P][HADDR(nn, cg)];                   \
      bf16x8 ahh1 = *(const bf16x8*)&h_hi[P][HADDR(nn, 4 + cg)];               \
      bf16x8 ahl0 = *(const bf16x8*)&h_lo[P][HADDR(nn, cg)];                   \
      bf16x8 ahl1 = *(const bf16x8*)&h_lo[P][HADDR(nn, 4 + cg)];               \
      f32x4 accs[4];                                                           \
      _Pragma("unroll")                                                        \
      for (int g = 0; g < 4; ++g) {                                            \
        f32x4 a0 = accx[P][g][wq * 64 + lane];                                 \
        f32x4 a1 = {0.f, 0.f, 0.f, 0.f};                                       \
        a0 = MFMA(ahh0, bhh[g][0], a0, 0, 0, 0);                               \
        a1 = MFMA(ahl0, bhh[g][0], a1, 0, 0, 0);                               \
        a0 = MFMA(ahh1, bhh[g][1], a0, 0, 0, 0);                               \
        a1 = MFMA(ahl1, bhh[g][1], a1, 0, 0, 0);                               \
        accs[g] = a0 + a1;                                                     \
      }                                                                        \
      _Pragma("unroll")                                                        \
      for (int r = 0; r < 4; ++r) {                                            \
        float iv = sigm(accs[0][r]);                                           \
        float fv = sigm(accs[1][r]);                                           \
        float gv = tanh_(accs[2][r]);                                          \
        float ov = sigm(accs[3][r]);                                           \
        cell[r] = fv * cell[r] + iv * gv;                                      \
        float hv = ov * tanh_(cell[r]);                                        \
        __bf16 h1 = (__bf16)hv;                                                \
        __bf16 h2 = (__bf16)(hv - (float)h1);                                  \
        int mrow = 4 * cg + r;                                                 \
        int ha = HADDR(mrow, uu >> 3) + (uu & 7);                              \
        h_hi[1 - (P)][ha] = h1;                                                \
        h_lo[1 - (P)][ha] = h2;                                                \
      }                                                                        \
    } else {                                                                   \
      if ((T0) > 0) {                                                          \
        _Pragma("unroll")                                                      \
        for (int r = 0; r < 4; ++r) {                                          \
          int mrow = 4 * cg + r;                                               \
          int ha = HADDR(mrow, uu >> 3) + (uu & 7);                            \
          unsigned int hb =                                                    \
              (unsigned int)__builtin_bit_cast(unsigned short, h_hi[P][ha])    \
            | ((unsigned int)__builtin_bit_cast(unsigned short, h_lo[P][ha]) << 16); \
          seqp[((size_t)(bbase + mrow) * T_LEN + (T0) - 1) * HDIM + uu] = hb;  \
        }                                                                      \
      }                                                                        \
      if ((T0) + 1 < T_LEN) {                                                  \
        bf16x8 xh0, xl0, xh1, xl1;                                             \
        unpk(xpk[P][0], xpk[P][1], &xh0, &xl0);                                \
        unpk(xpk[P][2], xpk[P][3], &xh1, &xl1);                                \
        _Pragma("unroll")                                                      \
        for (int g = 0; g < 4; ++g) {                                          \
          f32x4 a = {bias[g], bias[g], bias[g], bias[g]};                      \
          a = MFMA(xh0, bih[g][0], a, 0, 0, 0);                                \
          a = MFMA(xh1, bih[g][1], a, 0, 0, 0);                                \
          a = MFMA(xl0, bih[g][0], a, 0, 0, 0);                                \
          a = MFMA(xl1, bih[g][1], a, 0, 0, 0);                                \
          accx[1 - (P)][g][wq * 64 + lane] = a;                                \
        }                                                                      \
      }                                                                        \
      {                                                                        \
        int tp = (T0) + 3; if (tp >= T_LEN) tp = T_LEN - 1;                    \
        const unsigned int* px = seqp + xrow + (size_t)tp * HDIM;              \
        xpk[P][0] = *(const u32x4*)(px + 8 * cg);                              \
        xpk[P][1] = *(const u32x4*)(px + 8 * cg + 4);                          \
        xpk[P][2] = *(const u32x4*)(px + 32 + 8 * cg);                         \
        xpk[P][3] = *(const u32x4*)(px + 32 + 8 * cg + 4);                     \
      }                                                                        \
    }                                                                          \
    BARRIER();                                                                 \
  }

__global__ __launch_bounds__(512, 2)
void lstm_single(const float* __restrict__ w_ih,
                 const float* __restrict__ w_hh,
                 const float* __restrict__ b_ih,
                 const float* __restrict__ b_hh,
                 unsigned int* seqp)
{
    const int tid  = threadIdx.x;
    const int lane = tid & 63;
    const int wv   = tid >> 6;
    const bool isA = (wv < 4);
    const int wq   = wv & 3;
    const int nn   = lane & 15;
    const int cg   = lane >> 4;
    const int bbase = blockIdx.x * 16;
    const int grow = 16 * wq + nn;
    const int uu   = grow;

    __shared__ __align__(16) __bf16 h_hi[2][16 * 64];
    __shared__ __align__(16) __bf16 h_lo[2][16 * 64];
    __shared__ __align__(16) f32x4 accx[2][4][256];

    bf16x8 bhh[4][2];
    bf16x8 bih[4][2];
    float bias[4];
    if (isA) {
#pragma unroll
      for (int g = 0; g < 4; ++g)
#pragma unroll
        for (int kk = 0; kk < 2; ++kk) {
          const float* wp = w_hh + (size_t)(64 * g + grow) * 64 + kk * 32 + 8 * cg;
          bf16x8 t;
#pragma unroll
          for (int e = 0; e < 8; ++e) t[e] = (__bf16)wp[e];
          bhh[g][kk] = t;
        }
    } else {
#pragma unroll
      for (int g = 0; g < 4; ++g) {
        int row = 64 * g + grow;
        bias[g] = b_ih[row] + b_hh[row];
      }
#pragma unroll
      for (int g = 0; g < 4; ++g)
#pragma unroll
        for (int kk = 0; kk < 2; ++kk) {
          const float* wp = w_ih + (size_t)(64 * g + grow) * 64 + kk * 32 + 8 * cg;
          bf16x8 t;
#pragma unroll
          for (int e = 0; e < 8; ++e) t[e] = (__bf16)wp[e];
          bih[g][kk] = t;
        }
    }

    for (int q = tid; q < 1024; q += 512) {
      h_hi[0][q] = (__bf16)0.f; h_hi[1][q] = (__bf16)0.f;
      h_lo[0][q] = (__bf16)0.f; h_lo[1][q] = (__bf16)0.f;
    }

    float cell[4] = {0.f, 0.f, 0.f, 0.f};
    const size_t xrow = (size_t)(bbase + nn) * T_LEN * HDIM;
    u32x4 xpk[2][4];

    if (!isA) {
      const unsigned int* px = seqp + xrow;
      u32x4 q0 = *(const u32x4*)(px + 8 * cg);
      u32x4 q1 = *(const u32x4*)(px + 8 * cg + 4);
      u32x4 q2 = *(const u32x4*)(px + 32 + 8 * cg);
      u32x4 q3 = *(const u32x4*)(px + 32 + 8 * cg + 4);
      bf16x8 xh0, xl0, xh1, xl1;
      unpk(q0, q1, &xh0, &xl0);
      unpk(q2, q3, &xh1, &xl1);
#pragma unroll
      for (int g = 0; g < 4; ++g) {
        f32x4 a = {bias[g], bias[g], bias[g], bias[g]};
        a = MFMA(xh0, bih[g][0], a, 0, 0, 0);
        a = MFMA(xh1, bih[g][1], a, 0, 0, 0);
        a = MFMA(xl0, bih[g][0], a, 0, 0, 0);
        a = MFMA(xl1, bih[g][1], a, 0, 0, 0);
        accx[0][g][wq * 64 + lane] = a;
      }
#pragma unroll
      for (int p = 0; p < 2; ++p) {
        const unsigned int* pq = seqp + xrow + (size_t)(p + 1) * HDIM;
        xpk[p][0] = *(const u32x4*)(pq + 8 * cg);
        xpk[p][1] = *(const u32x4*)(pq + 8 * cg + 4);
        xpk[p][2] = *(const u32x4*)(pq + 32 + 8 * cg);
        xpk[p][3] = *(const u32x4*)(pq + 32 + 8 * cg + 4);
      }
    }
    __syncthreads();

    if (isA) __builtin_amdgcn_s_setprio(1);
    for (int t = 0; t < T_LEN; t += 2) {
      STEP(t, 0);
      STEP(t + 1, 1);
    }
    if (isA) __builtin_amdgcn_s_setprio(0);

    if (!isA) {
#pragma unroll
      for (int r = 0; r < 4; ++r) {
        int mrow = 4 * cg + r;
        int ha = HADDR(mrow, uu >> 3) + (uu & 7);
        unsigned int hb =
            (unsigned int)__builtin_bit_cast(unsigned short, h_hi[0][ha])
          | ((unsigned int)__builtin_bit_cast(unsigned short, h_lo[0][ha]) << 16);
        seqp[((size_t)(bbase + mrow) * T_LEN + (T_LEN - 1)) * HDIM + uu] = hb;
      }
    }
}

// FC head: out[b] = fc2_b + fc2_w . relu(fc1_b + fc1_w . h_T[b])
__global__ __launch_bounds__(256, 1)
void fc_head(const unsigned int* __restrict__ seqp,
             const float* __restrict__ fc1_w, const float* __restrict__ fc1_b,
             const float* __restrict__ fc2_w, const float* __restrict__ fc2_b,
             float* __restrict__ out)
{
    __shared__ float w1[FC1 * HDIM];
    __shared__ float b1[FC1];
    __shared__ float w2[FC1];
    const int tid = threadIdx.x;
    for (int i = tid; i < FC1 * HDIM; i += 256) w1[i] = fc1_w[i];
    if (tid < FC1) { b1[tid] = fc1_b[tid]; w2[tid] = fc2_w[tid]; }
    __syncthreads();

    const int b = blockIdx.x * 256 + tid;
    const size_t base = ((size_t)b * T_LEN + (T_LEN - 1)) * HDIM;
    float h[HDIM];
#pragma unroll
    for (int q = 0; q < HDIM; ++q) {
      unsigned int v = seqp[base + q];
      float hi = (float)__builtin_bit_cast(__bf16, (unsigned short)(v & 0xffffu));
      float lo = (float)__builtin_bit_cast(__bf16, (unsigned short)(v >> 16));
      h[q] = hi + lo;
    }
    float acc2 = fc2_b[0];
    for (int m = 0; m < FC1; ++m) {
      float a = b1[m];
#pragma unroll
      for (int q = 0; q < HDIM; ++q) a += w1[m * HDIM + q] * h[q];
      acc2 += w2[m] * fmaxf(a, 0.0f);
    }
    out[b] = acc2;
}

extern "C" void kernel_launch(void* const* d_in, const int* in_sizes, int n_in,
                              void* d_out, int out_size, void* d_ws, size_t ws_size,
                              hipStream_t stream) {
    const float* x         = (const float*)d_in[0];
    const float* w_ih0     = (const float*)d_in[1];
    const float* w_ih_rest = (const float*)d_in[2];
    const float* w_hh      = (const float*)d_in[3];
    const float* b_ih      = (const float*)d_in[4];
    const float* b_hh      = (const float*)d_in[5];
    const float* fc1_w     = (const float*)d_in[6];
    const float* fc1_b     = (const float*)d_in[7];
    const float* fc2_w     = (const float*)d_in[8];
    const float* fc2_b     = (const float*)d_in[9];
    float* out = (float*)d_out;

    unsigned int* seqp = (unsigned int*)d_ws;   // [B,T,64] packed = 256 MiB

    // layers 0+1, skew-2 pair; writes seq1
    lstm_pairq<0, true><<<dim3(B_TOT / 16), dim3(512), 0, stream>>>(
        x, w_ih0, w_ih_rest, w_hh, b_ih, b_hh, seqp);
    // layers 2+3, skew-2 pair; reads seq1 / writes seq3 in-place (gap >= 5)
    lstm_pairq<2, false><<<dim3(B_TOT / 16), dim3(512), 0, stream>>>(
        x, w_ih0, w_ih_rest, w_hh, b_ih, b_hh, seqp);
    // layer 4; reads seq3 / writes seq4 in-place (gap 4)
    lstm_single<<<dim3(B_TOT / 16), dim3(512), 0, stream>>>(
        w_ih_rest + (size_t)3 * 256 * HDIM,
        w_hh + (size_t)4 * 256 * HDIM,
        b_ih + (size_t)4 * 256,
        b_hh + (size_t)4 * 256,
        seqp);
    fc_head<<<dim3(B_TOT / 256), dim3(256), 0, stream>>>(
        seqp, fc1_w, fc1_b, fc2_w, fc2_b, out);
}

// Round 17
// 1187.305 us; speedup vs baseline: 7.1878x; 1.3651x over previous
//
#include <hip/hip_runtime.h>
#include <math.h>

#define B_TOT 2048
#define T_LEN 512
#define HDIM 64
#define FC1 50
#define NSUP 514   // skew-2 pair: 512 + 2

typedef __bf16 bf16x8 __attribute__((ext_vector_type(8)));
typedef float f32x4 __attribute__((ext_vector_type(4)));

// Fast transcendentals (no -ffast-math in harness; "/" would emit 12-inst IEEE div)
__device__ __forceinline__ float vrcp(float x) {
  float r; asm("v_rcp_f32 %0, %1" : "=v"(r) : "v"(x)); return r;
}
__device__ __forceinline__ float vexp2(float x) {
  float r; asm("v_exp_f32 %0, %1" : "=v"(r) : "v"(x)); return r;
}
__device__ __forceinline__ float sigm(float x) {
  return vrcp(1.0f + vexp2(x * -1.44269504088896340736f));
}
__device__ __forceinline__ float tanh_(float x) {
  return fmaf(2.0f, vrcp(1.0f + vexp2(x * -2.8853900817779268f)), -1.0f);
}

// lgkm-only barrier: LDS visibility without draining global queues.
#define BARRIER() asm volatile("s_waitcnt lgkmcnt(0)\n\ts_barrier" ::: "memory")
#define MFMA __builtin_amdgcn_mfma_f32_16x16x32_bf16

// Planar [16][64] bf16, 16B-chunk XOR swizzle: full-wave b128 = uniform 8 lanes/bank-group.
#define HADDR(row, chunk) (((row) << 6) + ((((chunk) ^ ((row) & 7))) << 3))

// ---------- Skew-2 pair kernel (R13 structure, PLAIN-bf16 h) ----------------
// R17: h carried as a single bf16 (no hi/lo split). Recurrence chain per gate
// = 2 chained MFMAs (vs 4), 2 ds_read_b128 (vs 4), no v_perm unpacking at all
// (global seq is planar bf16 -> direct bf16x8 loads). Cell state stays f32.
// Error budget: weight-quant alone gave absmax 1.22e-4; h-quant (bf16,
// ~0.2% rel, pseudo-random) predicted to land total ~1.5-3e-4 < 3.83e-4.
// DO NOT raise __launch_bounds__ past (512,2): (512,4)/(1024,*) trigger
// weight remat (R12/R14/R15: VGPR collapse, FETCH x40, 2-5x slowdowns).
#define SUPERQ(N_, P_)                                                         \
  {                                                                            \
    if (set == 0) {                                                            \
      if ((N_) < T_LEN) {                                                      \
        bf16x8 ah0 = *(const bf16x8*)&Hb[0][1 - (P_)][HADDR(nn, cg)];          \
        bf16x8 ah1 = *(const bf16x8*)&Hb[0][1 - (P_)][HADDR(nn, 4 + cg)];      \
        f32x4 accs[4];                                                         \
        _Pragma("unroll") for (int g = 0; g < 4; ++g) {                        \
          f32x4 a = xacc[P_][g];                                               \
          a = MFMA(ah0, bhh[g][0], a, 0, 0, 0);                                \
          a = MFMA(ah1, bhh[g][1], a, 0, 0, 0);                                \
          accs[g] = a;                                                         \
        }                                                                      \
        _Pragma("unroll") for (int r = 0; r < 4; ++r) {                        \
          float iv = sigm(accs[0][r]);                                         \
          float fv = sigm(accs[1][r]);                                         \
          float gv = tanh_(accs[2][r]);                                        \
          float ov = sigm(accs[3][r]);                                         \
          cell[r] = fv * cell[r] + iv * gv;                                    \
          float hv = ov * tanh_(cell[r]);                                      \
          __bf16 h1 = (__bf16)hv;                                              \
          int mrow = 4 * cg + r;                                               \
          Hb[0][P_][HADDR(mrow, uu >> 3) + (uu & 7)] = h1;                     \
        }                                                                      \
      }                                                                        \
      /* tail: x-seed for t = N_+1 */                                         \
      if ((N_) + 1 < T_LEN) {                                                  \
        if (XIN) {                                                             \
          _Pragma("unroll") for (int g = 0; g < 4; ++g) {                      \
            f32x4 a;                                                           \
            _Pragma("unroll") for (int r = 0; r < 4; ++r)                      \
              a[r] = bias[g] + xw[g*3+0] * xr[P_][r*3+0]                       \
                             + xw[g*3+1] * xr[P_][r*3+1]                       \
                             + xw[g*3+2] * xr[P_][r*3+2];                      \
            xacc[1 - (P_)][g] = a;                                             \
          }                                                                    \
        } else {                                                               \
          _Pragma("unroll") for (int g = 0; g < 4; ++g) {                      \
            f32x4 a = {bias[g], bias[g], bias[g], bias[g]};                    \
            a = MFMA(xfr[P_][0], bih[g][0], a, 0, 0, 0);                       \
            a = MFMA(xfr[P_][1], bih[g][1], a, 0, 0, 0);                       \
            xacc[1 - (P_)][g] = a;                                             \
          }                                                                    \
        }                                                                      \
      }                                                                        \
      {                                                                        \
        int tp = (N_) + 3; if (tp > T_LEN - 1) tp = T_LEN - 1;                 \
        if (XIN) {                                                             \
          _Pragma("unroll") for (int r = 0; r < 4; ++r)                        \
            _Pragma("unroll") for (int i = 0; i < 3; ++i)                      \
              xr[P_][r*3+i] =                                                  \
                  x_f32[((size_t)(bbase + 4*cg + r) * T_LEN + tp) * 3 + i];    \
        } else {                                                               \
          const __bf16* px = seqb + xrow + (size_t)tp * HDIM;                  \
          xfr[P_][0] = *(const bf16x8*)(px + 8 * cg);                          \
          xfr[P_][1] = *(const bf16x8*)(px + 32 + 8 * cg);                     \
        }                                                                      \
      }                                                                        \
    } else {                                                                   \
      if ((N_) >= 2) {                                                         \
        const int tl = (N_) - 2;                                               \
        bf16x8 ah0 = *(const bf16x8*)&Hb[1][1 - (P_)][HADDR(nn, cg)];          \
        bf16x8 ah1 = *(const bf16x8*)&Hb[1][1 - (P_)][HADDR(nn, 4 + cg)];      \
        f32x4 accs[4];                                                         \
        _Pragma("unroll") for (int g = 0; g < 4; ++g) {                        \
          f32x4 a = xacc[P_][g];                                               \
          a = MFMA(ah0, bhh[g][0], a, 0, 0, 0);                                \
          a = MFMA(ah1, bhh[g][1], a, 0, 0, 0);                                \
          accs[g] = a;                                                         \
        }                                                                      \
        _Pragma("unroll") for (int r = 0; r < 4; ++r) {                        \
          float iv = sigm(accs[0][r]);                                         \
          float fv = sigm(accs[1][r]);                                         \
          float gv = tanh_(accs[2][r]);                                        \
          float ov = sigm(accs[3][r]);                                         \
          cell[r] = fv * cell[r] + iv * gv;                                    \
          float hv = ov * tanh_(cell[r]);                                      \
          __bf16 h1 = (__bf16)hv;                                              \
          int mrow = 4 * cg + r;                                               \
          Hb[1][P_][HADDR(mrow, uu >> 3) + (uu & 7)] = h1;                     \
          seqb[((size_t)(bbase + mrow) * T_LEN + tl) * HDIM + uu] = h1;        \
        }                                                                      \
      }                                                                        \
      /* tail: x-seed for t = N_-1 from upstream h0(N_-1), pre-barrier data */ \
      if ((N_) >= 1 && (N_) - 1 < T_LEN) {                                     \
        bf16x8 xh0 = *(const bf16x8*)&Hb[0][1 - (P_)][HADDR(nn, cg)];          \
        bf16x8 xh1 = *(const bf16x8*)&Hb[0][1 - (P_)][HADDR(nn, 4 + cg)];      \
        _Pragma("unroll") for (int g = 0; g < 4; ++g) {                        \
          f32x4 a = {bias[g], bias[g], bias[g], bias[g]};                      \
          a = MFMA(xh0, bih[g][0], a, 0, 0, 0);                                \
          a = MFMA(xh1, bih[g][1], a, 0, 0, 0);                                \
          xacc[1 - (P_)][g] = a;                                               \
        }                                                                      \
      }                                                                        \
    }                                                                          \
    BARRIER();                                                                 \
  }

template<int L0, bool XIN>
__global__ __launch_bounds__(512, 2)   // DO NOT raise (remat hazard: R12/R14/R15)
void lstm_pairq(const float* __restrict__ x_f32,
                const float* __restrict__ w_ih0,
                const float* __restrict__ w_ih_rest,
                const float* __restrict__ w_hh,
                const float* __restrict__ b_ih,
                const float* __restrict__ b_hh,
                __bf16* __restrict__ seqb)
{
  const int tid  = threadIdx.x;
  const int lane = tid & 63;
  const int wv   = tid >> 6;
  const int set  = wv >> 2;       // 0,1 (wave-uniform)
  const int wq   = wv & 3;
  const int nn   = lane & 15;
  const int cg   = lane >> 4;
  const int bbase = blockIdx.x * 16;
  const int grow = 16 * wq + nn;
  const int uu   = grow;
  const int layer = L0 + set;

  __shared__ __align__(16) __bf16 Hb[2][2][1024];  // [set][parity], 4 KB

  bf16x8 bhh[4][2];
#pragma unroll
  for (int g = 0; g < 4; ++g)
#pragma unroll
    for (int kk = 0; kk < 2; ++kk) {
      const float* wp = w_hh + (size_t)layer * 256 * 64
                      + (size_t)(64 * g + grow) * 64 + kk * 32 + 8 * cg;
      bf16x8 t;
#pragma unroll
      for (int e = 0; e < 8; ++e) t[e] = (__bf16)wp[e];
      bhh[g][kk] = t;
    }
  bf16x8 bih[4][2];
  float xw[12];
  if (XIN && set == 0) {
#pragma unroll
    for (int g = 0; g < 4; ++g)
#pragma unroll
      for (int i = 0; i < 3; ++i) xw[g * 3 + i] = w_ih0[(64 * g + grow) * 3 + i];
  } else {
    const float* wih_l = w_ih_rest + (size_t)(layer - 1) * 256 * 64;
#pragma unroll
    for (int g = 0; g < 4; ++g)
#pragma unroll
      for (int kk = 0; kk < 2; ++kk) {
        const float* wp = wih_l + (size_t)(64 * g + grow) * 64 + kk * 32 + 8 * cg;
        bf16x8 t;
#pragma unroll
        for (int e = 0; e < 8; ++e) t[e] = (__bf16)wp[e];
        bih[g][kk] = t;
      }
  }
  float bias[4];
#pragma unroll
  for (int g = 0; g < 4; ++g) {
    int row = layer * 256 + 64 * g + grow;
    bias[g] = b_ih[row] + b_hh[row];
  }

  for (int q = tid; q < 4 * 1024; q += 512)
    ((__bf16*)Hb)[q] = (__bf16)0.f;

  float cell[4] = {0.f, 0.f, 0.f, 0.f};
  const size_t xrow = (size_t)(bbase + nn) * T_LEN * HDIM;

  f32x4 xacc[2][4];    // register x-seed, parity-indexed (macro-literal P_ only)
  float xr[2][12];     // set0 XIN queue
  bf16x8 xfr[2][2];    // set0 GIN queue (direct bf16 fragments, no unpack)

  if (set == 0) {
    if (XIN) {
      float x0[12];
#pragma unroll
      for (int r = 0; r < 4; ++r)
#pragma unroll
        for (int i = 0; i < 3; ++i)
          x0[r*3+i] = x_f32[((size_t)(bbase + 4*cg + r) * T_LEN + 0) * 3 + i];
#pragma unroll
      for (int g = 0; g < 4; ++g) {
        f32x4 a;
#pragma unroll
        for (int r = 0; r < 4; ++r)
          a[r] = bias[g] + xw[g*3+0]*x0[r*3+0] + xw[g*3+1]*x0[r*3+1] + xw[g*3+2]*x0[r*3+2];
        xacc[0][g] = a;
      }
#pragma unroll
      for (int p = 0; p < 2; ++p)
#pragma unroll
        for (int r = 0; r < 4; ++r)
#pragma unroll
          for (int i = 0; i < 3; ++i)
            xr[p][r*3+i] = x_f32[((size_t)(bbase + 4*cg + r) * T_LEN + (p + 1)) * 3 + i];
    } else {
      const __bf16* px = seqb + xrow;
      bf16x8 x0a = *(const bf16x8*)(px + 8 * cg);
      bf16x8 x0b = *(const bf16x8*)(px + 32 + 8 * cg);
#pragma unroll
      for (int g = 0; g < 4; ++g) {
        f32x4 a = {bias[g], bias[g], bias[g], bias[g]};
        a = MFMA(x0a, bih[g][0], a, 0, 0, 0);
        a = MFMA(x0b, bih[g][1], a, 0, 0, 0);
        xacc[0][g] = a;
      }
#pragma unroll
      for (int p = 0; p < 2; ++p) {
        const __bf16* pq = seqb + xrow + (size_t)(p + 1) * HDIM;
        xfr[p][0] = *(const bf16x8*)(pq + 8 * cg);
        xfr[p][1] = *(const bf16x8*)(pq + 32 + 8 * cg);
      }
    }
  }
  __syncthreads();

  for (int n = 0; n < NSUP; n += 2) {
    SUPERQ(n,     0);
    SUPERQ(n + 1, 1);
  }
}

// -------------- Single-layer kernel (layer 4, bf16 h; writes hT f32) --------
#define STEP(T0, P)                                                            \
  {                                                                            \
    if (isA) {                                                                 \
      bf16x8 ah0 = *(const bf16x8*)&h_b[P][HADDR(nn, cg)];                     \
      bf16x8 ah1 = *(const bf16x8*)&h_b[P][HADDR(nn, 4 + cg)];                 \
      f32x4 accs[4];                                                           \
      _Pragma("unroll")                                                        \
      for (int g = 0; g < 4; ++g) {                                            \
        f32x4 a = accx[P][g][wq * 64 + lane];                                  \
        a = MFMA(ah0, bhh[g][0], a, 0, 0, 0);                                  \
        a = MFMA(ah1, bhh[g][1], a, 0, 0, 0);                                  \
        accs[g] = a;                                                           \
      }                                                                        \
      _Pragma("unroll")                                                        \
      for (int r = 0; r < 4; ++r) {                                            \
        float iv = sigm(accs[0][r]);                                           \
        float fv = sigm(accs[1][r]);                                           \
        float gv = tanh_(accs[2][r]);                                          \
        float ov = sigm(accs[3][r]);                                           \
        cell[r] = fv * cell[r] + iv * gv;                                      \
        float hv = ov * tanh_(cell[r]);                                        \
        __bf16 h1 = (__bf16)hv;                                                \
        int mrow = 4 * cg + r;                                                 \
        h_b[1 - (P)][HADDR(mrow, uu >> 3) + (uu & 7)] = h1;                    \
        if ((T0) == T_LEN - 1)                                                 \
          hT[(size_t)(bbase + mrow) * HDIM + uu] = hv;  /* f32, no quant */    \
      }                                                                        \
    } else {                                                                   \
      if ((T0) + 1 < T_LEN) {                                                  \
        _Pragma("unroll")                                                      \
        for (int g = 0; g < 4; ++g) {                                          \
          f32x4 a = {bias[g], bias[g], bias[g], bias[g]};                      \
          a = MFMA(xfr[P][0], bih[g][0], a, 0, 0, 0);                          \
          a = MFMA(xfr[P][1], bih[g][1], a, 0, 0, 0);                          \
          accx[1 - (P)][g][wq * 64 + lane] = a;                                \
        }                                                                      \
      }                                                                        \
      {                                                                        \
        int tp = (T0) + 3; if (tp >= T_LEN) tp = T_LEN - 1;                    \
        const __bf16* px = seqb + xrow + (size_t)tp * HDIM;                    \
        xfr[P][0] = *(const bf16x8*)(px + 8 * cg);                             \
        xfr[P][1] = *(const bf16x8*)(px + 32 + 8 * cg);                        \
      }                                                                        \
    }                                                                          \
    BARRIER();                                                                 \
  }

__global__ __launch_bounds__(512, 2)
void lstm_single(const float* __restrict__ w_ih,
                 const float* __restrict__ w_hh,
                 const float* __restrict__ b_ih,
                 const float* __restrict__ b_hh,
                 const __bf16* __restrict__ seqb,
                 float* __restrict__ hT)
{
    const int tid  = threadIdx.x;
    const int lane = tid & 63;
    const int wv   = tid >> 6;
    const bool isA = (wv < 4);
    const int wq   = wv & 3;
    const int nn   = lane & 15;
    const int cg   = lane >> 4;
    const int bbase = blockIdx.x * 16;
    const int grow = 16 * wq + nn;
    const int uu   = grow;

    __shared__ __align__(16) __bf16 h_b[2][1024];        // 4 KB
    __shared__ __align__(16) f32x4 accx[2][4][256];      // 32 KB

    bf16x8 bhh[4][2];
    bf16x8 bih[4][2];
    float bias[4];
    if (isA) {
#pragma unroll
      for (int g = 0; g < 4; ++g)
#pragma unroll
        for (int kk = 0; kk < 2; ++kk) {
          const float* wp = w_hh + (size_t)(64 * g + grow) * 64 + kk * 32 + 8 * cg;
          bf16x8 t;
#pragma unroll
          for (int e = 0; e < 8; ++e) t[e] = (__bf16)wp[e];
          bhh[g][kk] = t;
        }
    } else {
#pragma unroll
      for (int g = 0; g < 4; ++g) {
        int row = 64 * g + grow;
        bias[g] = b_ih[row] + b_hh[row];
      }
#pragma unroll
      for (int g = 0; g < 4; ++g)
#pragma unroll
        for (int kk = 0; kk < 2; ++kk) {
          const float* wp = w_ih + (size_t)(64 * g + grow) * 64 + kk * 32 + 8 * cg;
          bf16x8 t;
#pragma unroll
          for (int e = 0; e < 8; ++e) t[e] = (__bf16)wp[e];
          bih[g][kk] = t;
        }
    }

    for (int q = tid; q < 2048; q += 512)
      ((__bf16*)h_b)[q] = (__bf16)0.f;

    float cell[4] = {0.f, 0.f, 0.f, 0.f};
    const size_t xrow = (size_t)(bbase + nn) * T_LEN * HDIM;
    bf16x8 xfr[2][2];

    if (!isA) {
      const __bf16* px = seqb + xrow;
      bf16x8 x0a = *(const bf16x8*)(px + 8 * cg);
      bf16x8 x0b = *(const bf16x8*)(px + 32 + 8 * cg);
#pragma unroll
      for (int g = 0; g < 4; ++g) {
        f32x4 a = {bias[g], bias[g], bias[g], bias[g]};
        a = MFMA(x0a, bih[g][0], a, 0, 0, 0);
        a = MFMA(x0b, bih[g][1], a, 0, 0, 0);
        accx[0][g][wq * 64 + lane] = a;
      }
#pragma unroll
      for (int p = 0; p < 2; ++p) {
        const __bf16* pq = seqb + xrow + (size_t)(p + 1) * HDIM;
        xfr[p][0] = *(const bf16x8*)(pq + 8 * cg);
        xfr[p][1] = *(const bf16x8*)(pq + 32 + 8 * cg);
      }
    }
    __syncthreads();

    if (isA) __builtin_amdgcn_s_setprio(1);
    for (int t = 0; t < T_LEN; t += 2) {
      STEP(t, 0);
      STEP(t + 1, 1);
    }
    if (isA) __builtin_amdgcn_s_setprio(0);
}

// FC head: out[b] = fc2_b + fc2_w . relu(fc1_b + fc1_w . hT[b]); hT is f32.
__global__ __launch_bounds__(256, 1)
void fc_head(const float* __restrict__ hT,
             const float* __restrict__ fc1_w, const float* __restrict__ fc1_b,
             const float* __restrict__ fc2_w, const float* __restrict__ fc2_b,
             float* __restrict__ out)
{
    __shared__ float w1[FC1 * HDIM];
    __shared__ float b1[FC1];
    __shared__ float w2[FC1];
    const int tid = threadIdx.x;
    for (int i = tid; i < FC1 * HDIM; i += 256) w1[i] = fc1_w[i];
    if (tid < FC1) { b1[tid] = fc1_b[tid]; w2[tid] = fc2_w[tid]; }
    __syncthreads();

    const int b = blockIdx.x * 256 + tid;
    float h[HDIM];
    const float4* hp = (const float4*)(hT + (size_t)b * HDIM);
#pragma unroll
    for (int q = 0; q < 16; ++q) {
      float4 v = hp[q];
      h[q*4+0] = v.x; h[q*4+1] = v.y; h[q*4+2] = v.z; h[q*4+3] = v.w;
    }
    float acc2 = fc2_b[0];
    for (int m = 0; m < FC1; ++m) {
      float a = b1[m];
#pragma unroll
      for (int q = 0; q < HDIM; ++q) a += w1[m * HDIM + q] * h[q];
      acc2 += w2[m] * fmaxf(a, 0.0f);
    }
    out[b] = acc2;
}

extern "C" void kernel_launch(void* const* d_in, const int* in_sizes, int n_in,
                              void* d_out, int out_size, void* d_ws, size_t ws_size,
                              hipStream_t stream) {
    const float* x         = (const float*)d_in[0];
    const float* w_ih0     = (const float*)d_in[1];
    const float* w_ih_rest = (const float*)d_in[2];
    const float* w_hh      = (const float*)d_in[3];
    const float* b_ih      = (const float*)d_in[4];
    const float* b_hh      = (const float*)d_in[5];
    const float* fc1_w     = (const float*)d_in[6];
    const float* fc1_b     = (const float*)d_in[7];
    const float* fc2_w     = (const float*)d_in[8];
    const float* fc2_b     = (const float*)d_in[9];
    float* out = (float*)d_out;

    __bf16* seqb = (__bf16*)d_ws;                                   // 128 MiB
    float* hT = (float*)(seqb + (size_t)B_TOT * T_LEN * HDIM);      // 512 KiB

    // layers 0+1, skew-2 pair; writes seq1 (bf16)
    lstm_pairq<0, true><<<dim3(B_TOT / 16), dim3(512), 0, stream>>>(
        x, w_ih0, w_ih_rest, w_hh, b_ih, b_hh, seqb);
    // layers 2+3, skew-2 pair; reads seq1 / writes seq3 in-place (gap >= 5)
    lstm_pairq<2, false><<<dim3(B_TOT / 16), dim3(512), 0, stream>>>(
        x, w_ih0, w_ih_rest, w_hh, b_ih, b_hh, seqb);
    // layer 4; reads seq3, writes hT f32 (A-wave epilogue, no quantization)
    lstm_single<<<dim3(B_TOT / 16), dim3(512), 0, stream>>>(
        w_ih_rest + (size_t)3 * 256 * HDIM,
        w_hh + (size_t)4 * 256 * HDIM,
        b_ih + (size_t)4 * 256,
        b_hh + (size_t)4 * 256,
        seqb, hT);
    fc_head<<<dim3(B_TOT / 256), dim3(256), 0, stream>>>(
        hT, fc1_w, fc1_b, fc2_w, fc2_b, out);
}